// Round 8
// baseline (883.863 us; speedup 1.0000x reference)
//
#include <hip/hip_runtime.h>
#include <math.h>

#define B_  32
#define N_  512
#define H_  128
#define E_  131072
#define T_  9
#define BN_ (B_*N_)
#define EPB 128  // edges per block in edge MFMA GEMM

typedef unsigned short ushort_t;
typedef __attribute__((ext_vector_type(8))) __bf16 bf16x8;
typedef __attribute__((ext_vector_type(8))) unsigned short ushort8;
typedef __attribute__((ext_vector_type(4))) float f32x4;

// split fp32 -> bf16 hi + bf16 lo (RNE both). v ~= hi + lo with ~2^-17 rel err.
__device__ __forceinline__ void split2(float v, ushort_t &h, ushort_t &l) {
    unsigned u = __builtin_bit_cast(unsigned, v);
    unsigned hb = (u + 0x7FFFu + ((u >> 16) & 1u)) & 0xFFFF0000u;
    h = (ushort_t)(hb >> 16);
    float lv = v - __builtin_bit_cast(float, hb);
    unsigned ul = __builtin_bit_cast(unsigned, lv);
    l = (ushort_t)((ul + 0x7FFFu + ((ul >> 16) & 1u)) >> 16);
}

// k-slot swizzle baked into global weight layout (G21: gload_lds dest linear,
// read applies same XOR). slot(k,n) = ((k>>3)&3) ^ ((n>>1)&3) -> 2-way banks.
__device__ __forceinline__ int kswz(int k, int n) {
    return (k & ~31) | (((((k >> 3) & 3) ^ ((n >> 1) & 3))) << 3) | (k & 7);
}

// meta layout (ints): [0..8]=cnt, [9..17]=start, [18..26]=off(atomic), [27..36]=cumBlocks(10)

// ---------------- fused histograms (type + target) ----------------
__global__ void count_all(const int* __restrict__ eids, int* __restrict__ meta,
                          int* __restrict__ tcnt) {
    __shared__ int lc[T_];
    if (threadIdx.x < T_) lc[threadIdx.x] = 0;
    __syncthreads();
    int e = blockIdx.x * 256 + threadIdx.x;
    if (e < E_) {
        int4 v = reinterpret_cast<const int4*>(eids)[e];
        atomicAdd(&lc[v.x], 1);
        atomicAdd(&tcnt[v.y * N_ + v.w], 1);
    }
    __syncthreads();
    if (threadIdx.x < T_ && lc[threadIdx.x]) atomicAdd(&meta[threadIdx.x], lc[threadIdx.x]);
}

__global__ void scan_types(int* meta) {
    int s = 0;
    for (int t = 0; t < T_; ++t) { meta[9 + t] = s; meta[18 + t] = s; s += meta[t]; }
    int cb = 0;
    for (int t = 0; t < T_; ++t) { meta[27 + t] = cb; cb += (meta[t] + EPB - 1) / EPB; }
    meta[27 + T_] = cb;
}

__global__ void scan_tgt(const int* __restrict__ tcnt, int* __restrict__ tstart,
                         int* __restrict__ toff) {
    __shared__ int bs[256];
    const int tid = threadIdx.x;
    const int chunk = BN_ / 256;   // 64
    const int base = tid * chunk;
    int s = 0;
    for (int i = 0; i < chunk; ++i) s += tcnt[base + i];
    bs[tid] = s;
    __syncthreads();
    if (tid == 0) { int acc = 0; for (int i = 0; i < 256; ++i) { int v = bs[i]; bs[i] = acc; acc += v; } }
    __syncthreads();
    int acc = bs[tid];
    for (int i = 0; i < chunk; ++i) {
        int v = tcnt[base + i];
        tstart[base + i] = acc; toff[base + i] = acc; acc += v;
    }
    if (tid == 255) tstart[BN_] = E_;
}

// ---------------- fused scatter (type perm + target rank) ----------------
__global__ void scatter_all(const int* __restrict__ eids, int* __restrict__ meta,
                            int* __restrict__ toff, int* __restrict__ perm,
                            int* __restrict__ rank) {
    __shared__ int lc[T_], lbase[T_];
    if (threadIdx.x < T_) lc[threadIdx.x] = 0;
    __syncthreads();
    int e = blockIdx.x * 256 + threadIdx.x;
    int4 v = {0, 0, 0, 0};
    int lp = 0;
    if (e < E_) { v = reinterpret_cast<const int4*>(eids)[e]; lp = atomicAdd(&lc[v.x], 1); }
    __syncthreads();
    if (threadIdx.x < T_ && lc[threadIdx.x])
        lbase[threadIdx.x] = atomicAdd(&meta[18 + threadIdx.x], lc[threadIdx.x]);
    __syncthreads();
    if (e < E_) {
        perm[lbase[v.x] + lp] = e;
        rank[e] = atomicAdd(&toff[v.y * N_ + v.w], 1);
    }
}

// ---------------- weight split/transpose for edge MFMA ----------------
// in: (T,H,H) = W[t][k][n]; out: (T,128,128) = [t][n][kswz(k,n)] bf16 hi/lo
__global__ void build_wt(const float* __restrict__ W,
                         ushort_t* __restrict__ wth, ushort_t* __restrict__ wtl) {
    int idx = blockIdx.x * 256 + threadIdx.x;
    if (idx >= T_ * H_ * H_) return;
    int t = idx / (H_ * H_);
    int rem = idx - t * H_ * H_;
    int n = rem >> 7, k = rem & 127;
    float v = W[(size_t)t * H_ * H_ + k * H_ + n];
    size_t o = (size_t)t * H_ * H_ + n * 128 + kswz(k, n);
    split2(v, wth[o], wtl[o]);
}

// ---------------- edge message GEMM via bf16x3 MFMA (128-edge blocks) ----------------
// Block = up to 128 edges of the SAME type. 4 waves 2x2; wave = 64 rows x 64 cols,
// frags 4(M) x 4(N), K chunks of 32.
__global__ __launch_bounds__(256) void edge_mfma(
    const float* __restrict__ h,
    const int*   __restrict__ eids,
    const int*   __restrict__ perm,
    const int*   __restrict__ rank,
    const int*   __restrict__ meta,
    const ushort_t* __restrict__ wth,  // (T,128,128) [t][n][k swz]
    const ushort_t* __restrict__ wtl,
    const float* __restrict__ bias,    // (T,H)
    float*       __restrict__ msg)     // (E,H) target-sorted
{
    __shared__ ushort_t Ah[2][EPB * 32], Al[2][EPB * 32];
    __shared__ ushort_t Bh[2][128 * 32], Bl[2][128 * 32];
    __shared__ int srcnode[EPB], outrow[EPB];
    __shared__ int info[3];
    const int tid = threadIdx.x;

    if (tid == 0) {
        int b = blockIdx.x;
        int nb = meta[27 + T_];
        if (b >= nb) info[0] = -1;
        else {
            int t = 0;
            while (b >= meta[27 + t + 1]) t++;
            int chunk = b - meta[27 + t];
            int c = meta[t] - chunk * EPB;
            info[0] = t;
            info[1] = meta[9 + t] + chunk * EPB;
            info[2] = (c > EPB) ? EPB : c;
        }
    }
    __syncthreads();
    const int t = info[0];
    if (t < 0) return;
    const int base = info[1], cnt = info[2];

    if (tid < EPB) {
        int e = perm[base + ((tid < cnt) ? tid : 0)];
        int eb = eids[e * 4 + 1];
        int es = eids[e * 4 + 2];
        srcnode[tid] = eb * N_ + es;
        outrow[tid]  = rank[e];
    }
    __syncthreads();

    const int w = tid >> 6, l = tid & 63;
    const int wr = (w >> 1) * 64, wc = (w & 1) * 64;
    const int l16 = l & 15, g = l >> 4;

    const int ar = tid >> 1;           // A row (2 threads/row)
    const int ab = (tid & 1) * 2;      // two 8-elem k blocks {ab, ab+1}
    const int bw = w * 32;             // B staging: wave's 32 B-rows

    f32x4 acc[4][4];
#pragma unroll
    for (int i = 0; i < 4; ++i)
#pragma unroll
        for (int j = 0; j < 4; ++j) acc[i][j] = (f32x4){0.f, 0.f, 0.f, 0.f};

    float4 pv[4];
    auto issueA = [&](int k0) {
        const float* sp = h + (size_t)srcnode[ar] * H_ + k0 + ab * 8;
#pragma unroll
        for (int i = 0; i < 4; ++i) pv[i] = reinterpret_cast<const float4*>(sp)[i];
    };
    auto writeA = [&](int buf) {
        __align__(16) ushort_t hv[16], lv[16];
#pragma unroll
        for (int i = 0; i < 4; ++i) {
            split2(pv[i].x, hv[i * 4 + 0], lv[i * 4 + 0]);
            split2(pv[i].y, hv[i * 4 + 1], lv[i * 4 + 1]);
            split2(pv[i].z, hv[i * 4 + 2], lv[i * 4 + 2]);
            split2(pv[i].w, hv[i * 4 + 3], lv[i * 4 + 3]);
        }
        const int x = (ar >> 1) & 3;
        const int p0 = ((ab + 0) ^ x) * 8;
        const int p1 = ((ab + 1) ^ x) * 8;
        *reinterpret_cast<ushort8*>(&Ah[buf][ar * 32 + p0]) = *reinterpret_cast<ushort8*>(&hv[0]);
        *reinterpret_cast<ushort8*>(&Ah[buf][ar * 32 + p1]) = *reinterpret_cast<ushort8*>(&hv[8]);
        *reinterpret_cast<ushort8*>(&Al[buf][ar * 32 + p0]) = *reinterpret_cast<ushort8*>(&lv[0]);
        *reinterpret_cast<ushort8*>(&Al[buf][ar * 32 + p1]) = *reinterpret_cast<ushort8*>(&lv[8]);
    };
    auto stageB = [&](int buf, int k0) {
#pragma unroll
        for (int q = 0; q < 2; ++q) {
            const int row = bw + q * 16 + (l >> 2);
            const size_t off = ((size_t)t * 128 + row) * 128 + k0 + (l & 3) * 8;
            __builtin_amdgcn_global_load_lds(
                (const __attribute__((address_space(1))) void*)(wth + off),
                (__attribute__((address_space(3))) void*)&Bh[buf][(bw + q * 16) * 32], 16, 0, 0);
            __builtin_amdgcn_global_load_lds(
                (const __attribute__((address_space(1))) void*)(wtl + off),
                (__attribute__((address_space(3))) void*)&Bl[buf][(bw + q * 16) * 32], 16, 0, 0);
        }
    };
    auto compute = [&](int buf) {
        bf16x8 fah[4], fal[4], fbh[4], fbl[4];
#pragma unroll
        for (int f = 0; f < 4; ++f) {
            const int arow = wr + f * 16 + l16;
            const int aoff = arow * 32 + ((g ^ ((arow >> 1) & 3)) * 8);
            fah[f] = *reinterpret_cast<const bf16x8*>(&Ah[buf][aoff]);
            fal[f] = *reinterpret_cast<const bf16x8*>(&Al[buf][aoff]);
            const int brow = wc + f * 16 + l16;
            const int boff = brow * 32 + ((g ^ ((brow >> 1) & 3)) * 8);
            fbh[f] = *reinterpret_cast<const bf16x8*>(&Bh[buf][boff]);
            fbl[f] = *reinterpret_cast<const bf16x8*>(&Bl[buf][boff]);
        }
#pragma unroll
        for (int mf = 0; mf < 4; ++mf)
#pragma unroll
            for (int nf = 0; nf < 4; ++nf)
                acc[mf][nf] = __builtin_amdgcn_mfma_f32_16x16x32_bf16(fah[mf], fbh[nf], acc[mf][nf], 0, 0, 0);
#pragma unroll
        for (int mf = 0; mf < 4; ++mf)
#pragma unroll
            for (int nf = 0; nf < 4; ++nf)
                acc[mf][nf] = __builtin_amdgcn_mfma_f32_16x16x32_bf16(fal[mf], fbh[nf], acc[mf][nf], 0, 0, 0);
#pragma unroll
        for (int mf = 0; mf < 4; ++mf)
#pragma unroll
            for (int nf = 0; nf < 4; ++nf)
                acc[mf][nf] = __builtin_amdgcn_mfma_f32_16x16x32_bf16(fah[mf], fbl[nf], acc[mf][nf], 0, 0, 0);
    };

    issueA(0); writeA(0); stageB(0, 0);
    int cur = 0;
    for (int ks = 0; ks < 4; ++ks) {
        __syncthreads();
        const bool more = (ks + 1 < 4);
        if (more) { issueA((ks + 1) * 32); stageB(cur ^ 1, (ks + 1) * 32); }
        compute(cur);
        if (more) writeA(cur ^ 1);
        cur ^= 1;
    }

    // epilogue: C/D layout col=lane&15, row=(lane>>4)*4+reg
#pragma unroll
    for (int mf = 0; mf < 4; ++mf) {
        const int rbase = wr + mf * 16 + g * 4;
#pragma unroll
        for (int nf = 0; nf < 4; ++nf) {
            const int col = wc + nf * 16 + l16;
            const float bv = bias[t * H_ + col];
#pragma unroll
            for (int r = 0; r < 4; ++r) {
                const int row = rbase + r;
                if (row < cnt)
                    msg[(size_t)outrow[row] * H_ + col] = acc[mf][nf][r] + bv;
            }
        }
    }
}

// ---------------- segmented aggregation (contiguous reads, no atomics) ----------------
__global__ __launch_bounds__(256) void aggregate(
    const float* __restrict__ msg,
    const int*   __restrict__ tstart,
    float*       __restrict__ agg)
{
    const int j = threadIdx.x & 127;
    const int n = blockIdx.x * 2 + (threadIdx.x >> 7);
    const int s = tstart[n], e_end = tstart[n + 1];
    float acc = 0.f;
    for (int i = s; i < e_end; ++i) acc += msg[(size_t)i * H_ + j];
    agg[(size_t)n * H_ + j] = acc;
}

// ---------------- B-hat build: split + transpose GRU weights (k-swizzled) ----------------
__global__ void build_bt(const float* __restrict__ W, const float* __restrict__ U,
                         const int Kx, const int K,
                         ushort_t* __restrict__ bth, ushort_t* __restrict__ btl)
{
    int idx = blockIdx.x * 256 + threadIdx.x;
    if (idx >= 512 * K) return;
    int n = idx / K, k = idx - n * K;
    int p = n >> 7;
    float v;
    if (p < 2)       v = (k < Kx) ? W[(size_t)k * 384 + n] : U[(size_t)(k - Kx) * 384 + n];
    else if (p == 2) v = (k < Kx) ? W[(size_t)k * 384 + n] : 0.f;
    else             v = (k >= Kx) ? U[(size_t)(k - Kx) * 384 + (n - 128)] : 0.f;
    size_t o = (size_t)n * K + kswz(k, n);
    split2(v, bth[o], btl[o]);
}

// ---------------- gates GEMM via bf16x3 MFMA: 128x128 tile, exact per-panel K ----------------
// panel = blockIdx.y: 0:z [0,K) | 1:r [0,K) | 2:xh [0,Kx) | 3:hh [Kx,K)
__global__ __launch_bounds__(256) void gates_mfma(
    const float* __restrict__ s0, const float* __restrict__ s1,
    const float* __restrict__ s2, const float* __restrict__ s3,
    const ushort_t* __restrict__ bth, const ushort_t* __restrict__ btl,
    const int K, float* __restrict__ gates)
{
    __shared__ ushort_t Ah[2][128 * 32], Al[2][128 * 32];
    __shared__ ushort_t Bh[2][128 * 32], Bl[2][128 * 32];
    const float* srcs[4] = {s0, s1, s2, s3};
    const int tid = threadIdx.x;
    const int m0 = blockIdx.x * 128;
    const int panel = blockIdx.y;
    const int Kx = K - 128;
    const int k_lo = (panel == 3) ? Kx : 0;
    const int k_hi = (panel == 2) ? Kx : K;
    const int w = tid >> 6, l = tid & 63;
    const int wr = (w >> 1) * 64, wc = (w & 1) * 64;
    const int l16 = l & 15, g = l >> 4;

    const int ar = tid >> 1;
    const int ab = (tid & 1) * 2;
    const int bw = w * 32;

    f32x4 acc[4][4];
#pragma unroll
    for (int i = 0; i < 4; ++i)
#pragma unroll
        for (int j = 0; j < 4; ++j) acc[i][j] = (f32x4){0.f, 0.f, 0.f, 0.f};

    float4 pv[4];
    auto issueA = [&](int kg) {
        const float* sp = srcs[kg >> 7] + (size_t)(m0 + ar) * H_ + (kg & 127) + ab * 8;
#pragma unroll
        for (int i = 0; i < 4; ++i) pv[i] = reinterpret_cast<const float4*>(sp)[i];
    };
    auto writeA = [&](int buf) {
        __align__(16) ushort_t hv[16], lv[16];
#pragma unroll
        for (int i = 0; i < 4; ++i) {
            split2(pv[i].x, hv[i * 4 + 0], lv[i * 4 + 0]);
            split2(pv[i].y, hv[i * 4 + 1], lv[i * 4 + 1]);
            split2(pv[i].z, hv[i * 4 + 2], lv[i * 4 + 2]);
            split2(pv[i].w, hv[i * 4 + 3], lv[i * 4 + 3]);
        }
        const int x = (ar >> 1) & 3;
        const int p0 = ((ab + 0) ^ x) * 8;
        const int p1 = ((ab + 1) ^ x) * 8;
        *reinterpret_cast<ushort8*>(&Ah[buf][ar * 32 + p0]) = *reinterpret_cast<ushort8*>(&hv[0]);
        *reinterpret_cast<ushort8*>(&Ah[buf][ar * 32 + p1]) = *reinterpret_cast<ushort8*>(&hv[8]);
        *reinterpret_cast<ushort8*>(&Al[buf][ar * 32 + p0]) = *reinterpret_cast<ushort8*>(&lv[0]);
        *reinterpret_cast<ushort8*>(&Al[buf][ar * 32 + p1]) = *reinterpret_cast<ushort8*>(&lv[8]);
    };
    auto stageB = [&](int buf, int k0) {
#pragma unroll
        for (int q = 0; q < 2; ++q) {
            const int row = bw + q * 16 + (l >> 2);
            const size_t off = (size_t)(panel * 128 + row) * K + k0 + (l & 3) * 8;
            __builtin_amdgcn_global_load_lds(
                (const __attribute__((address_space(1))) void*)(bth + off),
                (__attribute__((address_space(3))) void*)&Bh[buf][(bw + q * 16) * 32], 16, 0, 0);
            __builtin_amdgcn_global_load_lds(
                (const __attribute__((address_space(1))) void*)(btl + off),
                (__attribute__((address_space(3))) void*)&Bl[buf][(bw + q * 16) * 32], 16, 0, 0);
        }
    };
    auto compute = [&](int buf) {
        bf16x8 fah[4], fal[4], fbh[4], fbl[4];
#pragma unroll
        for (int f = 0; f < 4; ++f) {
            const int arow = wr + f * 16 + l16;
            const int aoff = arow * 32 + ((g ^ ((arow >> 1) & 3)) * 8);
            fah[f] = *reinterpret_cast<const bf16x8*>(&Ah[buf][aoff]);
            fal[f] = *reinterpret_cast<const bf16x8*>(&Al[buf][aoff]);
            const int brow = wc + f * 16 + l16;
            const int boff = brow * 32 + ((g ^ ((brow >> 1) & 3)) * 8);
            fbh[f] = *reinterpret_cast<const bf16x8*>(&Bh[buf][boff]);
            fbl[f] = *reinterpret_cast<const bf16x8*>(&Bl[buf][boff]);
        }
#pragma unroll
        for (int mf = 0; mf < 4; ++mf)
#pragma unroll
            for (int nf = 0; nf < 4; ++nf)
                acc[mf][nf] = __builtin_amdgcn_mfma_f32_16x16x32_bf16(fah[mf], fbh[nf], acc[mf][nf], 0, 0, 0);
#pragma unroll
        for (int mf = 0; mf < 4; ++mf)
#pragma unroll
            for (int nf = 0; nf < 4; ++nf)
                acc[mf][nf] = __builtin_amdgcn_mfma_f32_16x16x32_bf16(fal[mf], fbh[nf], acc[mf][nf], 0, 0, 0);
#pragma unroll
        for (int mf = 0; mf < 4; ++mf)
#pragma unroll
            for (int nf = 0; nf < 4; ++nf)
                acc[mf][nf] = __builtin_amdgcn_mfma_f32_16x16x32_bf16(fah[mf], fbl[nf], acc[mf][nf], 0, 0, 0);
    };

    issueA(k_lo); writeA(0); stageB(0, k_lo);
    int cur = 0;
    for (int ks = k_lo; ks < k_hi; ks += 32) {
        __syncthreads();
        const bool more = (ks + 32 < k_hi);
        if (more) { issueA(ks + 32); stageB(cur ^ 1, ks + 32); }
        compute(cur);
        if (more) writeA(cur ^ 1);
        cur ^= 1;
    }

    const int ncol0 = panel * 128;
#pragma unroll
    for (int mf = 0; mf < 4; ++mf) {
        const int row = m0 + wr + mf * 16 + g * 4;
#pragma unroll
        for (int nf = 0; nf < 4; ++nf) {
            const int col = ncol0 + wc + nf * 16 + l16;
#pragma unroll
            for (int r = 0; r < 4; ++r)
                gates[(size_t)(row + r) * 512 + col] = acc[mf][nf][r];
        }
    }
}

// ---------------- GRU elementwise (float4-vectorized) ----------------
__global__ __launch_bounds__(256) void gru_elem(
    const float* __restrict__ gates,
    const float* __restrict__ hcur,
    const float* __restrict__ b,     // (2,384) flat
    float*       __restrict__ hout)
{
    int u = blockIdx.x * 256 + threadIdx.x;      // over BN*32
    int n = u >> 5, jc = (u & 31) * 4;
    const float* gp = gates + (size_t)n * 512;
    float4 zp = *reinterpret_cast<const float4*>(&gp[jc]);
    float4 rp = *reinterpret_cast<const float4*>(&gp[128 + jc]);
    float4 xh = *reinterpret_cast<const float4*>(&gp[256 + jc]);
    float4 hh = *reinterpret_cast<const float4*>(&gp[384 + jc]);
    float4 hv = *reinterpret_cast<const float4*>(&hcur[(size_t)n * H_ + jc]);
    float4 ov;
#pragma unroll
    for (int q = 0; q < 4; ++q) {
        int j = jc + q;
        float z  = 1.f / (1.f + expf(-((&zp.x)[q] + b[j] + b[384 + j])));
        float rr = 1.f / (1.f + expf(-((&rp.x)[q] + b[128 + j] + b[512 + j])));
        float cand = tanhf((&xh.x)[q] + b[256 + j] + rr * ((&hh.x)[q] + b[640 + j]));
        (&ov.x)[q] = z * (&hv.x)[q] + (1.f - z) * cand;
    }
    *reinterpret_cast<float4*>(&hout[(size_t)n * H_ + jc]) = ov;
}

// ---------------- host orchestration ----------------
extern "C" void kernel_launch(void* const* d_in, const int* in_sizes, int n_in,
                              void* d_out, int out_size, void* d_ws, size_t ws_size,
                              hipStream_t stream) {
    const float* states = (const float*)d_in[0];
    const int*   eids   = (const int*)  d_in[1];
    const float* tw     = (const float*)d_in[2];   // (4,T,H,H)
    const float* tb     = (const float*)d_in[3];   // (4,T,H)
    const float* gW[4]  = { (const float*)d_in[4],  (const float*)d_in[7],
                            (const float*)d_in[10], (const float*)d_in[13] };
    const float* gU[4]  = { (const float*)d_in[5],  (const float*)d_in[8],
                            (const float*)d_in[11], (const float*)d_in[14] };
    const float* gb[4]  = { (const float*)d_in[6],  (const float*)d_in[9],
                            (const float*)d_in[12], (const float*)d_in[15] };
    float* out = (float*)d_out;

    const int KL[4]   = {256, 384, 256, 512};              // IN_DIM + 128 per layer
    const size_t KOFF[4] = {0, 512ull*256, 512ull*(256+384), 512ull*(256+384+256)};
    const size_t BT_TOT  = 512ull * (256 + 384 + 256 + 512);   // 720896 ushorts
    const size_t WT_L    = (size_t)T_ * H_ * H_;               // per-layer W plane

    char* ws = (char*)d_ws;
    float* bufA = (float*)ws; ws += (size_t)BN_ * H_ * 4;
    float* bufB = (float*)ws; ws += (size_t)BN_ * H_ * 4;
    float* bufC = (float*)ws; ws += (size_t)BN_ * H_ * 4;   // final layer-0 state
    float* agg  = (float*)ws; ws += (size_t)BN_ * H_ * 4;
    float* msg  = (float*)ws; ws += (size_t)E_ * H_ * 4;    // 64 MB; gates aliases it
    ushort_t* bthAll = (ushort_t*)ws; ws += BT_TOT * 2;
    ushort_t* btlAll = (ushort_t*)ws; ws += BT_TOT * 2;
    ushort_t* wthAll = (ushort_t*)ws; ws += 4 * WT_L * 2;   // (4,T,128,128) hi
    ushort_t* wtlAll = (ushort_t*)ws; ws += 4 * WT_L * 2;   // lo
    int*   perm  = (int*)ws;  ws += (size_t)E_ * 4;
    int*   rank  = (int*)ws;  ws += (size_t)E_ * 4;
    int*   tcnt  = (int*)ws;  ws += (size_t)BN_ * 4;
    int*   toff  = (int*)ws;  ws += (size_t)BN_ * 4;
    int*   tstart= (int*)ws;  ws += (size_t)(BN_ + 1) * 4;
    int*   meta  = (int*)ws;  ws += 64 * 4;
    float* gates = msg;   // msg dead after aggregate; 33.5MB < 64MB

    // ---- one-time sorts + weight splits ----
    hipMemsetAsync(meta, 0, 40 * sizeof(int), stream);
    hipMemsetAsync(tcnt, 0, BN_ * sizeof(int), stream);
    count_all<<<(E_ + 255) / 256, 256, 0, stream>>>(eids, meta, tcnt);
    scan_types<<<1, 1, 0, stream>>>(meta);
    scan_tgt  <<<1, 256, 0, stream>>>(tcnt, tstart, toff);
    scatter_all<<<(E_ + 255) / 256, 256, 0, stream>>>(eids, meta, toff, perm, rank);
    for (int lyr = 0; lyr < 4; ++lyr) {
        int K = KL[lyr];
        build_bt<<<(512 * K + 255) / 256, 256, 0, stream>>>(
            gW[lyr], gU[lyr], K - 128, K, bthAll + KOFF[lyr], btlAll + KOFF[lyr]);
        build_wt<<<((int)WT_L + 255) / 256, 256, 0, stream>>>(
            tw + lyr * WT_L, wthAll + lyr * WT_L, wtlAll + lyr * WT_L);
    }

    // step schedule: layers [0,0,0, 1, 2,2,2, 3]
    const int layer_of[8] = {0, 0, 0, 1, 2, 2, 2, 3};
    float* target[8] = {bufA, bufB, bufC, bufA, bufB, bufA, bufB, out};

    const float* cur = states;
    const int edge_grid = E_ / EPB + T_;

    for (int s = 0; s < 8; ++s) {
        const int l = layer_of[s];
        edge_mfma<<<edge_grid, 256, 0, stream>>>(
            cur, eids, perm, rank, meta,
            wthAll + l * WT_L, wtlAll + l * WT_L, tb + (size_t)l * T_ * H_, msg);
        aggregate<<<BN_ / 2, 256, 0, stream>>>(msg, tstart, agg);

        const float* s0; const float* s1; const float* s2; const float* s3;
        if (l == 0 || l == 2)      { s0 = agg;    s1 = cur;  s2 = nullptr; s3 = nullptr; }
        else if (l == 1)           { s0 = states; s1 = agg;  s2 = cur;     s3 = nullptr; }
        else                       { s0 = states; s1 = bufC; s2 = agg;     s3 = cur;     }

        dim3 ggrid(BN_ / 128, 4);
        gates_mfma<<<ggrid, 256, 0, stream>>>(s0, s1, s2, s3,
                                              bthAll + KOFF[l], btlAll + KOFF[l],
                                              KL[l], gates);

        float* nxt = target[s];
        gru_elem<<<BN_ * 32 / 256, 256, 0, stream>>>(gates, cur, gb[l], nxt);
        cur = nxt;
    }
}

// Round 9
// 731.736 us; speedup vs baseline: 1.2079x; 1.2079x over previous
//
#include <hip/hip_runtime.h>
#include <hip/hip_fp16.h>
#include <math.h>

#define B_  32
#define N_  512
#define H_  128
#define E_  131072
#define T_  9
#define BN_ (B_*N_)
#define EPB 64   // edges per block in edge MFMA GEMM (64: 48KB LDS -> 3 blocks/CU)

typedef unsigned short ushort_t;
typedef __attribute__((ext_vector_type(8))) __bf16 bf16x8;
typedef __attribute__((ext_vector_type(8))) unsigned short ushort8;
typedef __attribute__((ext_vector_type(4))) float f32x4;

// split fp32 -> bf16 hi + bf16 lo (RNE both). v ~= hi + lo with ~2^-17 rel err.
__device__ __forceinline__ void split2(float v, ushort_t &h, ushort_t &l) {
    unsigned u = __builtin_bit_cast(unsigned, v);
    unsigned hb = (u + 0x7FFFu + ((u >> 16) & 1u)) & 0xFFFF0000u;
    h = (ushort_t)(hb >> 16);
    float lv = v - __builtin_bit_cast(float, hb);
    unsigned ul = __builtin_bit_cast(unsigned, lv);
    l = (ushort_t)((ul + 0x7FFFu + ((ul >> 16) & 1u)) >> 16);
}

// k-slot swizzle baked into global weight layout (G21: gload_lds dest linear,
// read applies same XOR). slot(k,n) = ((k>>3)&3) ^ ((n>>1)&3) -> 2-way banks.
__device__ __forceinline__ int kswz(int k, int n) {
    return (k & ~31) | (((((k >> 3) & 3) ^ ((n >> 1) & 3))) << 3) | (k & 7);
}

// meta layout (ints): [0..8]=cnt, [9..17]=start, [18..26]=off(atomic), [27..36]=cumBlocks(10)

// ---------------- fused histograms (type + target) ----------------
__global__ void count_all(const int* __restrict__ eids, int* __restrict__ meta,
                          int* __restrict__ tcnt) {
    __shared__ int lc[T_];
    if (threadIdx.x < T_) lc[threadIdx.x] = 0;
    __syncthreads();
    int e = blockIdx.x * 256 + threadIdx.x;
    if (e < E_) {
        int4 v = reinterpret_cast<const int4*>(eids)[e];
        atomicAdd(&lc[v.x], 1);
        atomicAdd(&tcnt[v.y * N_ + v.w], 1);
    }
    __syncthreads();
    if (threadIdx.x < T_ && lc[threadIdx.x]) atomicAdd(&meta[threadIdx.x], lc[threadIdx.x]);
}

__global__ void scan_types(int* meta) {
    int s = 0;
    for (int t = 0; t < T_; ++t) { meta[9 + t] = s; meta[18 + t] = s; s += meta[t]; }
    int cb = 0;
    for (int t = 0; t < T_; ++t) { meta[27 + t] = cb; cb += (meta[t] + EPB - 1) / EPB; }
    meta[27 + T_] = cb;
}

__global__ void scan_tgt(const int* __restrict__ tcnt, int* __restrict__ tstart,
                         int* __restrict__ toff) {
    __shared__ int bs[256];
    const int tid = threadIdx.x;
    const int chunk = BN_ / 256;   // 64
    const int base = tid * chunk;
    int s = 0;
    for (int i = 0; i < chunk; ++i) s += tcnt[base + i];
    bs[tid] = s;
    __syncthreads();
    if (tid == 0) { int acc = 0; for (int i = 0; i < 256; ++i) { int v = bs[i]; bs[i] = acc; acc += v; } }
    __syncthreads();
    int acc = bs[tid];
    for (int i = 0; i < chunk; ++i) {
        int v = tcnt[base + i];
        tstart[base + i] = acc; toff[base + i] = acc; acc += v;
    }
    if (tid == 255) tstart[BN_] = E_;
}

// ---------------- fused scatter (type perm + target rank) ----------------
__global__ void scatter_all(const int* __restrict__ eids, int* __restrict__ meta,
                            int* __restrict__ toff, int* __restrict__ perm,
                            int* __restrict__ rank) {
    __shared__ int lc[T_], lbase[T_];
    if (threadIdx.x < T_) lc[threadIdx.x] = 0;
    __syncthreads();
    int e = blockIdx.x * 256 + threadIdx.x;
    int4 v = {0, 0, 0, 0};
    int lp = 0;
    if (e < E_) { v = reinterpret_cast<const int4*>(eids)[e]; lp = atomicAdd(&lc[v.x], 1); }
    __syncthreads();
    if (threadIdx.x < T_ && lc[threadIdx.x])
        lbase[threadIdx.x] = atomicAdd(&meta[18 + threadIdx.x], lc[threadIdx.x]);
    __syncthreads();
    if (e < E_) {
        perm[lbase[v.x] + lp] = e;
        rank[e] = atomicAdd(&toff[v.y * N_ + v.w], 1);
    }
}

// ---------------- weight split/transpose for edge MFMA ----------------
// in: (T,H,H) = W[t][k][n]; out: (T,128,128) = [t][n][kswz(k,n)] bf16 hi/lo
__global__ void build_wt(const float* __restrict__ W,
                         ushort_t* __restrict__ wth, ushort_t* __restrict__ wtl) {
    int idx = blockIdx.x * 256 + threadIdx.x;
    if (idx >= T_ * H_ * H_) return;
    int t = idx / (H_ * H_);
    int rem = idx - t * H_ * H_;
    int n = rem >> 7, k = rem & 127;
    float v = W[(size_t)t * H_ * H_ + k * H_ + n];
    size_t o = (size_t)t * H_ * H_ + n * 128 + kswz(k, n);
    split2(v, wth[o], wtl[o]);
}

// ---------------- edge message GEMM via bf16x3 MFMA (64-edge blocks) ----------------
// Block = up to 64 edges of the SAME type. 4 waves 2x2; wave = 32 rows x 64 cols,
// frags 2(M) x 4(N), K chunks of 32. msg written fp16 (target-sorted).
__global__ __launch_bounds__(256) void edge_mfma(
    const float* __restrict__ h,
    const int*   __restrict__ eids,
    const int*   __restrict__ perm,
    const int*   __restrict__ rank,
    const int*   __restrict__ meta,
    const ushort_t* __restrict__ wth,  // (T,128,128) [t][n][k swz]
    const ushort_t* __restrict__ wtl,
    const float* __restrict__ bias,    // (T,H)
    ushort_t*    __restrict__ msg16)   // (E,H) fp16, target-sorted
{
    __shared__ ushort_t Ah[2][EPB * 32], Al[2][EPB * 32];
    __shared__ ushort_t Bh[2][128 * 32], Bl[2][128 * 32];
    __shared__ int srcnode[EPB], outrow[EPB];
    __shared__ int info[3];
    const int tid = threadIdx.x;

    if (tid == 0) {
        int b = blockIdx.x;
        int nb = meta[27 + T_];
        if (b >= nb) info[0] = -1;
        else {
            int t = 0;
            while (b >= meta[27 + t + 1]) t++;
            int chunk = b - meta[27 + t];
            int c = meta[t] - chunk * EPB;
            info[0] = t;
            info[1] = meta[9 + t] + chunk * EPB;
            info[2] = (c > EPB) ? EPB : c;
        }
    }
    __syncthreads();
    const int t = info[0];
    if (t < 0) return;
    const int base = info[1], cnt = info[2];

    if (tid < EPB) {
        int e = perm[base + ((tid < cnt) ? tid : 0)];
        int eb = eids[e * 4 + 1];
        int es = eids[e * 4 + 2];
        srcnode[tid] = eb * N_ + es;
        outrow[tid]  = rank[e];
    }
    __syncthreads();

    const int w = tid >> 6, l = tid & 63;
    const int wr = (w >> 1) * 32, wc = (w & 1) * 64;
    const int l16 = l & 15, g = l >> 4;

    const int ar = tid >> 2;          // A row (4 threads/row)
    const int kb = tid & 3;           // 8-elem k block
    const int bw = w * 32;            // B staging: wave's 32 B-rows

    f32x4 acc[2][4];
#pragma unroll
    for (int i = 0; i < 2; ++i)
#pragma unroll
        for (int j = 0; j < 4; ++j) acc[i][j] = (f32x4){0.f, 0.f, 0.f, 0.f};

    float4 pv[2];
    auto issueA = [&](int k0) {
        const float* sp = h + (size_t)srcnode[ar] * H_ + k0 + kb * 8;
        pv[0] = reinterpret_cast<const float4*>(sp)[0];
        pv[1] = reinterpret_cast<const float4*>(sp)[1];
    };
    auto writeA = [&](int buf) {
        __align__(16) ushort_t hv[8], lv[8];
        split2(pv[0].x, hv[0], lv[0]); split2(pv[0].y, hv[1], lv[1]);
        split2(pv[0].z, hv[2], lv[2]); split2(pv[0].w, hv[3], lv[3]);
        split2(pv[1].x, hv[4], lv[4]); split2(pv[1].y, hv[5], lv[5]);
        split2(pv[1].z, hv[6], lv[6]); split2(pv[1].w, hv[7], lv[7]);
        const int p = (kb ^ ((ar >> 1) & 3)) * 8;
        *reinterpret_cast<ushort8*>(&Ah[buf][ar * 32 + p]) = *reinterpret_cast<ushort8*>(hv);
        *reinterpret_cast<ushort8*>(&Al[buf][ar * 32 + p]) = *reinterpret_cast<ushort8*>(lv);
    };
    auto stageB = [&](int buf, int k0) {
#pragma unroll
        for (int q = 0; q < 2; ++q) {
            const int row = bw + q * 16 + (l >> 2);
            const size_t off = ((size_t)t * 128 + row) * 128 + k0 + (l & 3) * 8;
            __builtin_amdgcn_global_load_lds(
                (const __attribute__((address_space(1))) void*)(wth + off),
                (__attribute__((address_space(3))) void*)&Bh[buf][(bw + q * 16) * 32], 16, 0, 0);
            __builtin_amdgcn_global_load_lds(
                (const __attribute__((address_space(1))) void*)(wtl + off),
                (__attribute__((address_space(3))) void*)&Bl[buf][(bw + q * 16) * 32], 16, 0, 0);
        }
    };
    auto compute = [&](int buf) {
        bf16x8 fah[2], fal[2], fbh[4], fbl[4];
#pragma unroll
        for (int f = 0; f < 2; ++f) {
            const int arow = wr + f * 16 + l16;
            const int aoff = arow * 32 + ((g ^ ((arow >> 1) & 3)) * 8);
            fah[f] = *reinterpret_cast<const bf16x8*>(&Ah[buf][aoff]);
            fal[f] = *reinterpret_cast<const bf16x8*>(&Al[buf][aoff]);
        }
#pragma unroll
        for (int f = 0; f < 4; ++f) {
            const int brow = wc + f * 16 + l16;
            const int boff = brow * 32 + ((g ^ ((brow >> 1) & 3)) * 8);
            fbh[f] = *reinterpret_cast<const bf16x8*>(&Bh[buf][boff]);
            fbl[f] = *reinterpret_cast<const bf16x8*>(&Bl[buf][boff]);
        }
#pragma unroll
        for (int mf = 0; mf < 2; ++mf)
#pragma unroll
            for (int nf = 0; nf < 4; ++nf)
                acc[mf][nf] = __builtin_amdgcn_mfma_f32_16x16x32_bf16(fah[mf], fbh[nf], acc[mf][nf], 0, 0, 0);
#pragma unroll
        for (int mf = 0; mf < 2; ++mf)
#pragma unroll
            for (int nf = 0; nf < 4; ++nf)
                acc[mf][nf] = __builtin_amdgcn_mfma_f32_16x16x32_bf16(fal[mf], fbh[nf], acc[mf][nf], 0, 0, 0);
#pragma unroll
        for (int mf = 0; mf < 2; ++mf)
#pragma unroll
            for (int nf = 0; nf < 4; ++nf)
                acc[mf][nf] = __builtin_amdgcn_mfma_f32_16x16x32_bf16(fah[mf], fbl[nf], acc[mf][nf], 0, 0, 0);
    };

    issueA(0); writeA(0); stageB(0, 0);
    int cur = 0;
    for (int ks = 0; ks < 4; ++ks) {
        __syncthreads();
        const bool more = (ks + 1 < 4);
        if (more) { issueA((ks + 1) * 32); stageB(cur ^ 1, (ks + 1) * 32); }
        compute(cur);
        if (more) writeA(cur ^ 1);
        cur ^= 1;
    }

    // epilogue: C/D layout col=lane&15, row=(lane>>4)*4+reg; fp16 store
#pragma unroll
    for (int mf = 0; mf < 2; ++mf) {
        const int rbase = wr + mf * 16 + g * 4;
#pragma unroll
        for (int nf = 0; nf < 4; ++nf) {
            const int col = wc + nf * 16 + l16;
            const float bv = bias[t * H_ + col];
#pragma unroll
            for (int r = 0; r < 4; ++r) {
                const int row = rbase + r;
                if (row < cnt)
                    msg16[(size_t)outrow[row] * H_ + col] =
                        __builtin_bit_cast(ushort_t, __float2half(acc[mf][nf][r] + bv));
            }
        }
    }
}

// ---------------- segmented aggregation (fp16 in, fp32 out; no atomics) ----------------
// 8 nodes/block; 32 lanes per node, 4 cols each (8B ushort4 reads, fully coalesced).
__global__ __launch_bounds__(256) void aggregate(
    const ushort_t* __restrict__ msg16,
    const int*      __restrict__ tstart,
    float*          __restrict__ agg)
{
    const int n  = blockIdx.x * 8 + (threadIdx.x >> 5);
    const int jc = (threadIdx.x & 31) * 4;
    const int s = tstart[n], e_end = tstart[n + 1];
    float a0 = 0.f, a1 = 0.f, a2 = 0.f, a3 = 0.f;
    for (int i = s; i < e_end; ++i) {
        ushort4 u = *reinterpret_cast<const ushort4*>(&msg16[(size_t)i * H_ + jc]);
        a0 += __half2float(__builtin_bit_cast(__half, u.x));
        a1 += __half2float(__builtin_bit_cast(__half, u.y));
        a2 += __half2float(__builtin_bit_cast(__half, u.z));
        a3 += __half2float(__builtin_bit_cast(__half, u.w));
    }
    float4 o = make_float4(a0, a1, a2, a3);
    *reinterpret_cast<float4*>(&agg[(size_t)n * H_ + jc]) = o;
}

// ---------------- B-hat build: split + transpose GRU weights (k-swizzled) ----------------
__global__ void build_bt(const float* __restrict__ W, const float* __restrict__ U,
                         const int Kx, const int K,
                         ushort_t* __restrict__ bth, ushort_t* __restrict__ btl)
{
    int idx = blockIdx.x * 256 + threadIdx.x;
    if (idx >= 512 * K) return;
    int n = idx / K, k = idx - n * K;
    int p = n >> 7;
    float v;
    if (p < 2)       v = (k < Kx) ? W[(size_t)k * 384 + n] : U[(size_t)(k - Kx) * 384 + n];
    else if (p == 2) v = (k < Kx) ? W[(size_t)k * 384 + n] : 0.f;
    else             v = (k >= Kx) ? U[(size_t)(k - Kx) * 384 + (n - 128)] : 0.f;
    size_t o = (size_t)n * K + kswz(k, n);
    split2(v, bth[o], btl[o]);
}

// ---------------- gates GEMM via bf16x3 MFMA: 128x128 tile, exact per-panel K ----------------
// panel = blockIdx.y: 0:z [0,K) | 1:r [0,K) | 2:xh [0,Kx) | 3:hh [Kx,K)
__global__ __launch_bounds__(256) void gates_mfma(
    const float* __restrict__ s0, const float* __restrict__ s1,
    const float* __restrict__ s2, const float* __restrict__ s3,
    const ushort_t* __restrict__ bth, const ushort_t* __restrict__ btl,
    const int K, float* __restrict__ gates)
{
    __shared__ ushort_t Ah[2][128 * 32], Al[2][128 * 32];
    __shared__ ushort_t Bh[2][128 * 32], Bl[2][128 * 32];
    const float* srcs[4] = {s0, s1, s2, s3};
    const int tid = threadIdx.x;
    const int m0 = blockIdx.x * 128;
    const int panel = blockIdx.y;
    const int Kx = K - 128;
    const int k_lo = (panel == 3) ? Kx : 0;
    const int k_hi = (panel == 2) ? Kx : K;
    const int w = tid >> 6, l = tid & 63;
    const int wr = (w >> 1) * 64, wc = (w & 1) * 64;
    const int l16 = l & 15, g = l >> 4;

    const int ar = tid >> 1;
    const int ab = (tid & 1) * 2;
    const int bw = w * 32;

    f32x4 acc[4][4];
#pragma unroll
    for (int i = 0; i < 4; ++i)
#pragma unroll
        for (int j = 0; j < 4; ++j) acc[i][j] = (f32x4){0.f, 0.f, 0.f, 0.f};

    float4 pv[4];
    auto issueA = [&](int kg) {
        const float* sp = srcs[kg >> 7] + (size_t)(m0 + ar) * H_ + (kg & 127) + ab * 8;
#pragma unroll
        for (int i = 0; i < 4; ++i) pv[i] = reinterpret_cast<const float4*>(sp)[i];
    };
    auto writeA = [&](int buf) {
        __align__(16) ushort_t hv[16], lv[16];
#pragma unroll
        for (int i = 0; i < 4; ++i) {
            split2(pv[i].x, hv[i * 4 + 0], lv[i * 4 + 0]);
            split2(pv[i].y, hv[i * 4 + 1], lv[i * 4 + 1]);
            split2(pv[i].z, hv[i * 4 + 2], lv[i * 4 + 2]);
            split2(pv[i].w, hv[i * 4 + 3], lv[i * 4 + 3]);
        }
        const int x = (ar >> 1) & 3;
        const int p0 = ((ab + 0) ^ x) * 8;
        const int p1 = ((ab + 1) ^ x) * 8;
        *reinterpret_cast<ushort8*>(&Ah[buf][ar * 32 + p0]) = *reinterpret_cast<ushort8*>(&hv[0]);
        *reinterpret_cast<ushort8*>(&Ah[buf][ar * 32 + p1]) = *reinterpret_cast<ushort8*>(&hv[8]);
        *reinterpret_cast<ushort8*>(&Al[buf][ar * 32 + p0]) = *reinterpret_cast<ushort8*>(&lv[0]);
        *reinterpret_cast<ushort8*>(&Al[buf][ar * 32 + p1]) = *reinterpret_cast<ushort8*>(&lv[8]);
    };
    auto stageB = [&](int buf, int k0) {
#pragma unroll
        for (int q = 0; q < 2; ++q) {
            const int row = bw + q * 16 + (l >> 2);
            const size_t off = (size_t)(panel * 128 + row) * K + k0 + (l & 3) * 8;
            __builtin_amdgcn_global_load_lds(
                (const __attribute__((address_space(1))) void*)(bth + off),
                (__attribute__((address_space(3))) void*)&Bh[buf][(bw + q * 16) * 32], 16, 0, 0);
            __builtin_amdgcn_global_load_lds(
                (const __attribute__((address_space(1))) void*)(btl + off),
                (__attribute__((address_space(3))) void*)&Bl[buf][(bw + q * 16) * 32], 16, 0, 0);
        }
    };
    auto compute = [&](int buf) {
        bf16x8 fah[4], fal[4], fbh[4], fbl[4];
#pragma unroll
        for (int f = 0; f < 4; ++f) {
            const int arow = wr + f * 16 + l16;
            const int aoff = arow * 32 + ((g ^ ((arow >> 1) & 3)) * 8);
            fah[f] = *reinterpret_cast<const bf16x8*>(&Ah[buf][aoff]);
            fal[f] = *reinterpret_cast<const bf16x8*>(&Al[buf][aoff]);
            const int brow = wc + f * 16 + l16;
            const int boff = brow * 32 + ((g ^ ((brow >> 1) & 3)) * 8);
            fbh[f] = *reinterpret_cast<const bf16x8*>(&Bh[buf][boff]);
            fbl[f] = *reinterpret_cast<const bf16x8*>(&Bl[buf][boff]);
        }
#pragma unroll
        for (int mf = 0; mf < 4; ++mf)
#pragma unroll
            for (int nf = 0; nf < 4; ++nf)
                acc[mf][nf] = __builtin_amdgcn_mfma_f32_16x16x32_bf16(fah[mf], fbh[nf], acc[mf][nf], 0, 0, 0);
#pragma unroll
        for (int mf = 0; mf < 4; ++mf)
#pragma unroll
            for (int nf = 0; nf < 4; ++nf)
                acc[mf][nf] = __builtin_amdgcn_mfma_f32_16x16x32_bf16(fal[mf], fbh[nf], acc[mf][nf], 0, 0, 0);
#pragma unroll
        for (int mf = 0; mf < 4; ++mf)
#pragma unroll
            for (int nf = 0; nf < 4; ++nf)
                acc[mf][nf] = __builtin_amdgcn_mfma_f32_16x16x32_bf16(fah[mf], fbl[nf], acc[mf][nf], 0, 0, 0);
    };

    issueA(k_lo); writeA(0); stageB(0, k_lo);
    int cur = 0;
    for (int ks = k_lo; ks < k_hi; ks += 32) {
        __syncthreads();
        const bool more = (ks + 32 < k_hi);
        if (more) { issueA(ks + 32); stageB(cur ^ 1, ks + 32); }
        compute(cur);
        if (more) writeA(cur ^ 1);
        cur ^= 1;
    }

    const int ncol0 = panel * 128;
#pragma unroll
    for (int mf = 0; mf < 4; ++mf) {
        const int row = m0 + wr + mf * 16 + g * 4;
#pragma unroll
        for (int nf = 0; nf < 4; ++nf) {
            const int col = ncol0 + wc + nf * 16 + l16;
#pragma unroll
            for (int r = 0; r < 4; ++r)
                gates[(size_t)(row + r) * 512 + col] = acc[mf][nf][r];
        }
    }
}

// ---------------- GRU elementwise (float4-vectorized) ----------------
__global__ __launch_bounds__(256) void gru_elem(
    const float* __restrict__ gates,
    const float* __restrict__ hcur,
    const float* __restrict__ b,     // (2,384) flat
    float*       __restrict__ hout)
{
    int u = blockIdx.x * 256 + threadIdx.x;      // over BN*32
    int n = u >> 5, jc = (u & 31) * 4;
    const float* gp = gates + (size_t)n * 512;
    float4 zp = *reinterpret_cast<const float4*>(&gp[jc]);
    float4 rp = *reinterpret_cast<const float4*>(&gp[128 + jc]);
    float4 xh = *reinterpret_cast<const float4*>(&gp[256 + jc]);
    float4 hh = *reinterpret_cast<const float4*>(&gp[384 + jc]);
    float4 hv = *reinterpret_cast<const float4*>(&hcur[(size_t)n * H_ + jc]);
    float4 ov;
#pragma unroll
    for (int q = 0; q < 4; ++q) {
        int j = jc + q;
        float z  = 1.f / (1.f + expf(-((&zp.x)[q] + b[j] + b[384 + j])));
        float rr = 1.f / (1.f + expf(-((&rp.x)[q] + b[128 + j] + b[512 + j])));
        float cand = tanhf((&xh.x)[q] + b[256 + j] + rr * ((&hh.x)[q] + b[640 + j]));
        (&ov.x)[q] = z * (&hv.x)[q] + (1.f - z) * cand;
    }
    *reinterpret_cast<float4*>(&hout[(size_t)n * H_ + jc]) = ov;
}

// ---------------- host orchestration ----------------
extern "C" void kernel_launch(void* const* d_in, const int* in_sizes, int n_in,
                              void* d_out, int out_size, void* d_ws, size_t ws_size,
                              hipStream_t stream) {
    const float* states = (const float*)d_in[0];
    const int*   eids   = (const int*)  d_in[1];
    const float* tw     = (const float*)d_in[2];   // (4,T,H,H)
    const float* tb     = (const float*)d_in[3];   // (4,T,H)
    const float* gW[4]  = { (const float*)d_in[4],  (const float*)d_in[7],
                            (const float*)d_in[10], (const float*)d_in[13] };
    const float* gU[4]  = { (const float*)d_in[5],  (const float*)d_in[8],
                            (const float*)d_in[11], (const float*)d_in[14] };
    const float* gb[4]  = { (const float*)d_in[6],  (const float*)d_in[9],
                            (const float*)d_in[12], (const float*)d_in[15] };
    float* out = (float*)d_out;

    const int KL[4]   = {256, 384, 256, 512};              // IN_DIM + 128 per layer
    const size_t KOFF[4] = {0, 512ull*256, 512ull*(256+384), 512ull*(256+384+256)};
    const size_t BT_TOT  = 512ull * (256 + 384 + 256 + 512);   // 720896 ushorts
    const size_t WT_L    = (size_t)T_ * H_ * H_;               // per-layer W plane

    char* ws = (char*)d_ws;
    float* bufA = (float*)ws; ws += (size_t)BN_ * H_ * 4;
    float* bufB = (float*)ws; ws += (size_t)BN_ * H_ * 4;
    float* bufC = (float*)ws; ws += (size_t)BN_ * H_ * 4;   // final layer-0 state
    float* agg  = (float*)ws; ws += (size_t)BN_ * H_ * 4;
    char*  msgR = ws;         ws += (size_t)E_ * H_ * 4;    // 64MB region: msg16 + gates alias
    ushort_t* bthAll = (ushort_t*)ws; ws += BT_TOT * 2;
    ushort_t* btlAll = (ushort_t*)ws; ws += BT_TOT * 2;
    ushort_t* wthAll = (ushort_t*)ws; ws += 4 * WT_L * 2;   // (4,T,128,128) hi
    ushort_t* wtlAll = (ushort_t*)ws; ws += 4 * WT_L * 2;   // lo
    int*   perm  = (int*)ws;  ws += (size_t)E_ * 4;
    int*   rank  = (int*)ws;  ws += (size_t)E_ * 4;
    int*   tcnt  = (int*)ws;  ws += (size_t)BN_ * 4;
    int*   toff  = (int*)ws;  ws += (size_t)BN_ * 4;
    int*   tstart= (int*)ws;  ws += (size_t)(BN_ + 1) * 4;
    int*   meta  = (int*)ws;  ws += 64 * 4;
    ushort_t* msg16 = (ushort_t*)msgR;   // 33.5MB fp16
    float*    gates = (float*)msgR;      // 33.5MB fp32 (msg16 dead after aggregate; serial)

    // ---- one-time sorts + weight splits ----
    hipMemsetAsync(meta, 0, 40 * sizeof(int), stream);
    hipMemsetAsync(tcnt, 0, BN_ * sizeof(int), stream);
    count_all<<<(E_ + 255) / 256, 256, 0, stream>>>(eids, meta, tcnt);
    scan_types<<<1, 1, 0, stream>>>(meta);
    scan_tgt  <<<1, 256, 0, stream>>>(tcnt, tstart, toff);
    scatter_all<<<(E_ + 255) / 256, 256, 0, stream>>>(eids, meta, toff, perm, rank);
    for (int lyr = 0; lyr < 4; ++lyr) {
        int K = KL[lyr];
        build_bt<<<(512 * K + 255) / 256, 256, 0, stream>>>(
            gW[lyr], gU[lyr], K - 128, K, bthAll + KOFF[lyr], btlAll + KOFF[lyr]);
        build_wt<<<((int)WT_L + 255) / 256, 256, 0, stream>>>(
            tw + lyr * WT_L, wthAll + lyr * WT_L, wtlAll + lyr * WT_L);
    }

    // step schedule: layers [0,0,0, 1, 2,2,2, 3]
    const int layer_of[8] = {0, 0, 0, 1, 2, 2, 2, 3};
    float* target[8] = {bufA, bufB, bufC, bufA, bufB, bufA, bufB, out};

    const float* cur = states;
    const int edge_grid = E_ / EPB + T_;

    for (int s = 0; s < 8; ++s) {
        const int l = layer_of[s];
        edge_mfma<<<edge_grid, 256, 0, stream>>>(
            cur, eids, perm, rank, meta,
            wthAll + l * WT_L, wtlAll + l * WT_L, tb + (size_t)l * T_ * H_, msg16);
        aggregate<<<BN_ / 8, 256, 0, stream>>>(msg16, tstart, agg);

        const float* s0; const float* s1; const float* s2; const float* s3;
        if (l == 0 || l == 2)      { s0 = agg;    s1 = cur;  s2 = nullptr; s3 = nullptr; }
        else if (l == 1)           { s0 = states; s1 = agg;  s2 = cur;     s3 = nullptr; }
        else                       { s0 = states; s1 = bufC; s2 = agg;     s3 = cur;     }

        dim3 ggrid(BN_ / 128, 4);
        gates_mfma<<<ggrid, 256, 0, stream>>>(s0, s1, s2, s3,
                                              bthAll + KOFF[l], btlAll + KOFF[l],
                                              KL[l], gates);

        float* nxt = target[s];
        gru_elem<<<BN_ * 32 / 256, 256, 0, stream>>>(gates, cur, gb[l], nxt);
        cur = nxt;
    }
}

// Round 10
// 722.368 us; speedup vs baseline: 1.2236x; 1.0130x over previous
//
#include <hip/hip_runtime.h>
#include <hip/hip_fp16.h>
#include <math.h>

#define B_  32
#define N_  512
#define H_  128
#define E_  131072
#define T_  9
#define BN_ (B_*N_)
#define EPB 64   // edges per block in edge MFMA GEMM (48KB LDS -> 3 blocks/CU)

typedef unsigned short ushort_t;
typedef __attribute__((ext_vector_type(8))) __bf16 bf16x8;
typedef __attribute__((ext_vector_type(8))) unsigned short ushort8;
typedef __attribute__((ext_vector_type(4))) float f32x4;

// split fp32 -> bf16 hi + bf16 lo (RNE both). v ~= hi + lo with ~2^-17 rel err.
__device__ __forceinline__ void split2(float v, ushort_t &h, ushort_t &l) {
    unsigned u = __builtin_bit_cast(unsigned, v);
    unsigned hb = (u + 0x7FFFu + ((u >> 16) & 1u)) & 0xFFFF0000u;
    h = (ushort_t)(hb >> 16);
    float lv = v - __builtin_bit_cast(float, hb);
    unsigned ul = __builtin_bit_cast(unsigned, lv);
    l = (ushort_t)((ul + 0x7FFFu + ((ul >> 16) & 1u)) >> 16);
}

// k-slot swizzle baked into global weight layout (G21). phys slot of logical k.
__device__ __forceinline__ int kswz(int k, int n) {
    return (k & ~31) | (((((k >> 3) & 3) ^ ((n >> 1) & 3))) << 3) | (k & 7);
}

// meta layout (ints): [0..8]=cnt, [9..17]=start, [18..26]=off(atomic), [27..36]=cumBlocks(10)

// ---------------- fused histograms (type + target) ----------------
__global__ void count_all(const int* __restrict__ eids, int* __restrict__ meta,
                          int* __restrict__ tcnt) {
    __shared__ int lc[T_];
    if (threadIdx.x < T_) lc[threadIdx.x] = 0;
    __syncthreads();
    int e = blockIdx.x * 256 + threadIdx.x;
    if (e < E_) {
        int4 v = reinterpret_cast<const int4*>(eids)[e];
        atomicAdd(&lc[v.x], 1);
        atomicAdd(&tcnt[v.y * N_ + v.w], 1);
    }
    __syncthreads();
    if (threadIdx.x < T_ && lc[threadIdx.x]) atomicAdd(&meta[threadIdx.x], lc[threadIdx.x]);
}

__global__ void scan_types(int* meta) {
    int s = 0;
    for (int t = 0; t < T_; ++t) { meta[9 + t] = s; meta[18 + t] = s; s += meta[t]; }
    int cb = 0;
    for (int t = 0; t < T_; ++t) { meta[27 + t] = cb; cb += (meta[t] + EPB - 1) / EPB; }
    meta[27 + T_] = cb;
}

__global__ void scan_tgt(const int* __restrict__ tcnt, int* __restrict__ tstart,
                         int* __restrict__ toff) {
    __shared__ int bs[256];
    const int tid = threadIdx.x;
    const int chunk = BN_ / 256;   // 64
    const int base = tid * chunk;
    int s = 0;
    for (int i = 0; i < chunk; ++i) s += tcnt[base + i];
    bs[tid] = s;
    __syncthreads();
    if (tid == 0) { int acc = 0; for (int i = 0; i < 256; ++i) { int v = bs[i]; bs[i] = acc; acc += v; } }
    __syncthreads();
    int acc = bs[tid];
    for (int i = 0; i < chunk; ++i) {
        int v = tcnt[base + i];
        tstart[base + i] = acc; toff[base + i] = acc; acc += v;
    }
    if (tid == 255) tstart[BN_] = E_;
}

// ---------------- fused scatter (type perm + target rank) ----------------
__global__ void scatter_all(const int* __restrict__ eids, int* __restrict__ meta,
                            int* __restrict__ toff, int* __restrict__ perm,
                            int* __restrict__ rank) {
    __shared__ int lc[T_], lbase[T_];
    if (threadIdx.x < T_) lc[threadIdx.x] = 0;
    __syncthreads();
    int e = blockIdx.x * 256 + threadIdx.x;
    int4 v = {0, 0, 0, 0};
    int lp = 0;
    if (e < E_) { v = reinterpret_cast<const int4*>(eids)[e]; lp = atomicAdd(&lc[v.x], 1); }
    __syncthreads();
    if (threadIdx.x < T_ && lc[threadIdx.x])
        lbase[threadIdx.x] = atomicAdd(&meta[18 + threadIdx.x], lc[threadIdx.x]);
    __syncthreads();
    if (e < E_) {
        perm[lbase[v.x] + lp] = e;
        rank[e] = atomicAdd(&toff[v.y * N_ + v.w], 1);
    }
}

// ---------------- state split: fp32 (BN,H) -> bf16 hi/lo planes ----------------
__global__ __launch_bounds__(256) void split_state(const float* __restrict__ in,
                                                   ushort_t* __restrict__ hP,
                                                   ushort_t* __restrict__ lP) {
    int i = blockIdx.x * 256 + threadIdx.x;      // over BN*H/4
    float4 v = reinterpret_cast<const float4*>(in)[i];
    ushort4 h, l;
    split2(v.x, h.x, l.x); split2(v.y, h.y, l.y);
    split2(v.z, h.z, l.z); split2(v.w, h.w, l.w);
    reinterpret_cast<ushort4*>(hP)[i] = h;
    reinterpret_cast<ushort4*>(lP)[i] = l;
}

// ---------------- weight split/transpose for edge MFMA ----------------
__global__ void build_wt(const float* __restrict__ W,
                         ushort_t* __restrict__ wth, ushort_t* __restrict__ wtl) {
    int idx = blockIdx.x * 256 + threadIdx.x;
    if (idx >= T_ * H_ * H_) return;
    int t = idx / (H_ * H_);
    int rem = idx - t * H_ * H_;
    int n = rem >> 7, k = rem & 127;
    float v = W[(size_t)t * H_ * H_ + k * H_ + n];
    size_t o = (size_t)t * H_ * H_ + n * 128 + kswz(k, n);
    split2(v, wth[o], wtl[o]);
}

// ---------------- edge message GEMM via bf16x3 MFMA (64-edge blocks) ----------------
// A staged from pre-split hi/lo planes via global_load_lds (per-lane gather source,
// pre-swizzled; linear LDS dest). No in-kernel split.
__global__ __launch_bounds__(256) void edge_mfma(
    const ushort_t* __restrict__ hH,   // (BN,H) bf16-hi plane of current state
    const ushort_t* __restrict__ hL,   // lo plane
    const int*   __restrict__ eids,
    const int*   __restrict__ perm,
    const int*   __restrict__ rank,
    const int*   __restrict__ meta,
    const ushort_t* __restrict__ wth,  // (T,128,128) [t][n][k swz]
    const ushort_t* __restrict__ wtl,
    const float* __restrict__ bias,    // (T,H)
    ushort_t*    __restrict__ msg16)   // (E,H) fp16, target-sorted
{
    __shared__ ushort_t Ah[2][EPB * 32], Al[2][EPB * 32];
    __shared__ ushort_t Bh[2][128 * 32], Bl[2][128 * 32];
    __shared__ int srcnode[EPB], outrow[EPB];
    __shared__ int info[3];
    const int tid = threadIdx.x;

    if (tid == 0) {
        int b = blockIdx.x;
        int nb = meta[27 + T_];
        if (b >= nb) info[0] = -1;
        else {
            int t = 0;
            while (b >= meta[27 + t + 1]) t++;
            int chunk = b - meta[27 + t];
            int c = meta[t] - chunk * EPB;
            info[0] = t;
            info[1] = meta[9 + t] + chunk * EPB;
            info[2] = (c > EPB) ? EPB : c;
        }
    }
    __syncthreads();
    const int t = info[0];
    if (t < 0) return;
    const int base = info[1], cnt = info[2];

    if (tid < EPB) {
        int e = perm[base + ((tid < cnt) ? tid : 0)];
        int eb = eids[e * 4 + 1];
        int es = eids[e * 4 + 2];
        srcnode[tid] = eb * N_ + es;
        outrow[tid]  = rank[e];
    }
    __syncthreads();

    const int w = tid >> 6, l = tid & 63;
    const int wr = (w >> 1) * 32, wc = (w & 1) * 64;
    const int l16 = l & 15, g = l >> 4;

    // A staging: lane (row=tid>>2, slot=tid&3); wave w covers rows 16w..16w+15
    const int arow_st = tid >> 2;
    const int aswz = ((tid & 3) ^ ((arow_st >> 1) & 3)) * 8;   // pre-swizzled k-group
    const int nodeReg = srcnode[arow_st];
    const int bw = w * 32;            // B staging: wave's 32 B-rows

    f32x4 acc[2][4];
#pragma unroll
    for (int i = 0; i < 2; ++i)
#pragma unroll
        for (int j = 0; j < 4; ++j) acc[i][j] = (f32x4){0.f, 0.f, 0.f, 0.f};

    auto stageA = [&](int buf, int k0) {
        const size_t off = (size_t)nodeReg * H_ + k0 + aswz;
        __builtin_amdgcn_global_load_lds(
            (const __attribute__((address_space(1))) void*)(hH + off),
            (__attribute__((address_space(3))) void*)&Ah[buf][w * 16 * 32], 16, 0, 0);
        __builtin_amdgcn_global_load_lds(
            (const __attribute__((address_space(1))) void*)(hL + off),
            (__attribute__((address_space(3))) void*)&Al[buf][w * 16 * 32], 16, 0, 0);
    };
    auto stageB = [&](int buf, int k0) {
#pragma unroll
        for (int q = 0; q < 2; ++q) {
            const int row = bw + q * 16 + (l >> 2);
            const size_t off = ((size_t)t * 128 + row) * 128 + k0 + (l & 3) * 8;
            __builtin_amdgcn_global_load_lds(
                (const __attribute__((address_space(1))) void*)(wth + off),
                (__attribute__((address_space(3))) void*)&Bh[buf][(bw + q * 16) * 32], 16, 0, 0);
            __builtin_amdgcn_global_load_lds(
                (const __attribute__((address_space(1))) void*)(wtl + off),
                (__attribute__((address_space(3))) void*)&Bl[buf][(bw + q * 16) * 32], 16, 0, 0);
        }
    };
    auto compute = [&](int buf) {
        bf16x8 fah[2], fal[2], fbh[4], fbl[4];
#pragma unroll
        for (int f = 0; f < 2; ++f) {
            const int arow = wr + f * 16 + l16;
            const int aoff = arow * 32 + ((g ^ ((arow >> 1) & 3)) * 8);
            fah[f] = *reinterpret_cast<const bf16x8*>(&Ah[buf][aoff]);
            fal[f] = *reinterpret_cast<const bf16x8*>(&Al[buf][aoff]);
        }
#pragma unroll
        for (int f = 0; f < 4; ++f) {
            const int brow = wc + f * 16 + l16;
            const int boff = brow * 32 + ((g ^ ((brow >> 1) & 3)) * 8);
            fbh[f] = *reinterpret_cast<const bf16x8*>(&Bh[buf][boff]);
            fbl[f] = *reinterpret_cast<const bf16x8*>(&Bl[buf][boff]);
        }
#pragma unroll
        for (int mf = 0; mf < 2; ++mf)
#pragma unroll
            for (int nf = 0; nf < 4; ++nf)
                acc[mf][nf] = __builtin_amdgcn_mfma_f32_16x16x32_bf16(fah[mf], fbh[nf], acc[mf][nf], 0, 0, 0);
#pragma unroll
        for (int mf = 0; mf < 2; ++mf)
#pragma unroll
            for (int nf = 0; nf < 4; ++nf)
                acc[mf][nf] = __builtin_amdgcn_mfma_f32_16x16x32_bf16(fal[mf], fbh[nf], acc[mf][nf], 0, 0, 0);
#pragma unroll
        for (int mf = 0; mf < 2; ++mf)
#pragma unroll
            for (int nf = 0; nf < 4; ++nf)
                acc[mf][nf] = __builtin_amdgcn_mfma_f32_16x16x32_bf16(fah[mf], fbl[nf], acc[mf][nf], 0, 0, 0);
    };

    stageA(0, 0); stageB(0, 0);
    int cur = 0;
    for (int ks = 0; ks < 4; ++ks) {
        __syncthreads();
        const bool more = (ks + 1 < 4);
        if (more) { stageA(cur ^ 1, (ks + 1) * 32); stageB(cur ^ 1, (ks + 1) * 32); }
        compute(cur);
        cur ^= 1;
    }

    // epilogue: C/D layout col=lane&15, row=(lane>>4)*4+reg; fp16 store
#pragma unroll
    for (int mf = 0; mf < 2; ++mf) {
        const int rbase = wr + mf * 16 + g * 4;
#pragma unroll
        for (int nf = 0; nf < 4; ++nf) {
            const int col = wc + nf * 16 + l16;
            const float bv = bias[t * H_ + col];
#pragma unroll
            for (int r = 0; r < 4; ++r) {
                const int row = rbase + r;
                if (row < cnt)
                    msg16[(size_t)outrow[row] * H_ + col] =
                        __builtin_bit_cast(ushort_t, __float2half(acc[mf][nf][r] + bv));
            }
        }
    }
}

// ---------------- segmented aggregation (fp16 in; fp32 + hi/lo planes out) ----------------
__global__ __launch_bounds__(256) void aggregate(
    const ushort_t* __restrict__ msg16,
    const int*      __restrict__ tstart,
    float*          __restrict__ agg,
    ushort_t*       __restrict__ agH,
    ushort_t*       __restrict__ agL)
{
    const int n  = blockIdx.x * 8 + (threadIdx.x >> 5);
    const int jc = (threadIdx.x & 31) * 4;
    const int s = tstart[n], e_end = tstart[n + 1];
    float a0 = 0.f, a1 = 0.f, a2 = 0.f, a3 = 0.f;
    for (int i = s; i < e_end; ++i) {
        ushort4 u = *reinterpret_cast<const ushort4*>(&msg16[(size_t)i * H_ + jc]);
        a0 += __half2float(__builtin_bit_cast(__half, u.x));
        a1 += __half2float(__builtin_bit_cast(__half, u.y));
        a2 += __half2float(__builtin_bit_cast(__half, u.z));
        a3 += __half2float(__builtin_bit_cast(__half, u.w));
    }
    const size_t o = (size_t)n * H_ + jc;
    *reinterpret_cast<float4*>(&agg[o]) = make_float4(a0, a1, a2, a3);
    ushort4 h, l;
    split2(a0, h.x, l.x); split2(a1, h.y, l.y);
    split2(a2, h.z, l.z); split2(a3, h.w, l.w);
    *reinterpret_cast<ushort4*>(&agH[o]) = h;
    *reinterpret_cast<ushort4*>(&agL[o]) = l;
}

// ---------------- B-hat build: split + transpose GRU weights (k-swizzled) ----------------
__global__ void build_bt(const float* __restrict__ W, const float* __restrict__ U,
                         const int Kx, const int K,
                         ushort_t* __restrict__ bth, ushort_t* __restrict__ btl)
{
    int idx = blockIdx.x * 256 + threadIdx.x;
    if (idx >= 512 * K) return;
    int n = idx / K, k = idx - n * K;
    int p = n >> 7;
    float v;
    if (p < 2)       v = (k < Kx) ? W[(size_t)k * 384 + n] : U[(size_t)(k - Kx) * 384 + n];
    else if (p == 2) v = (k < Kx) ? W[(size_t)k * 384 + n] : 0.f;
    else             v = (k >= Kx) ? U[(size_t)(k - Kx) * 384 + (n - 128)] : 0.f;
    size_t o = (size_t)n * K + kswz(k, n);
    split2(v, bth[o], btl[o]);
}

// ---------------- gates GEMM via bf16x3 MFMA: 128x128 tile, exact per-panel K ----------------
// A staged from pre-split planes via global_load_lds (pre-swizzled source; linear dest).
// panel = blockIdx.y: 0:z [0,K) | 1:r [0,K) | 2:xh [0,Kx) | 3:hh [Kx,K)
__global__ __launch_bounds__(256) void gates_mfma(
    const ushort_t* __restrict__ s0H, const ushort_t* __restrict__ s0L,
    const ushort_t* __restrict__ s1H, const ushort_t* __restrict__ s1L,
    const ushort_t* __restrict__ s2H, const ushort_t* __restrict__ s2L,
    const ushort_t* __restrict__ s3H, const ushort_t* __restrict__ s3L,
    const ushort_t* __restrict__ bth, const ushort_t* __restrict__ btl,
    const int K, float* __restrict__ gates)
{
    __shared__ ushort_t Ah[2][128 * 32], Al[2][128 * 32];
    __shared__ ushort_t Bh[2][128 * 32], Bl[2][128 * 32];
    const ushort_t* sH[4] = {s0H, s1H, s2H, s3H};
    const ushort_t* sL[4] = {s0L, s1L, s2L, s3L};
    const int tid = threadIdx.x;
    const int m0 = blockIdx.x * 128;
    const int panel = blockIdx.y;
    const int Kx = K - 128;
    const int k_lo = (panel == 3) ? Kx : 0;
    const int k_hi = (panel == 2) ? Kx : K;
    const int w = tid >> 6, l = tid & 63;
    const int wr = (w >> 1) * 64, wc = (w & 1) * 64;
    const int l16 = l & 15, g = l >> 4;

    const int bw = w * 32;

    f32x4 acc[4][4];
#pragma unroll
    for (int i = 0; i < 4; ++i)
#pragma unroll
        for (int j = 0; j < 4; ++j) acc[i][j] = (f32x4){0.f, 0.f, 0.f, 0.f};

    auto stageA = [&](int buf, int kg0) {
        const ushort_t* spH = sH[kg0 >> 7];
        const ushort_t* spL = sL[kg0 >> 7];
        const int kc = kg0 & 127;
#pragma unroll
        for (int q = 0; q < 2; ++q) {
            const int row = q * 64 + (tid >> 2);
            const int kg = ((tid & 3) ^ ((row >> 1) & 3)) * 8;
            const size_t off = (size_t)(m0 + row) * H_ + kc + kg;
            __builtin_amdgcn_global_load_lds(
                (const __attribute__((address_space(1))) void*)(spH + off),
                (__attribute__((address_space(3))) void*)&Ah[buf][(q * 64 + w * 16) * 32], 16, 0, 0);
            __builtin_amdgcn_global_load_lds(
                (const __attribute__((address_space(1))) void*)(spL + off),
                (__attribute__((address_space(3))) void*)&Al[buf][(q * 64 + w * 16) * 32], 16, 0, 0);
        }
    };
    auto stageB = [&](int buf, int k0) {
#pragma unroll
        for (int q = 0; q < 2; ++q) {
            const int row = bw + q * 16 + (l >> 2);
            const size_t off = (size_t)(panel * 128 + row) * K + k0 + (l & 3) * 8;
            __builtin_amdgcn_global_load_lds(
                (const __attribute__((address_space(1))) void*)(bth + off),
                (__attribute__((address_space(3))) void*)&Bh[buf][(bw + q * 16) * 32], 16, 0, 0);
            __builtin_amdgcn_global_load_lds(
                (const __attribute__((address_space(1))) void*)(btl + off),
                (__attribute__((address_space(3))) void*)&Bl[buf][(bw + q * 16) * 32], 16, 0, 0);
        }
    };
    auto compute = [&](int buf) {
        bf16x8 fah[4], fal[4], fbh[4], fbl[4];
#pragma unroll
        for (int f = 0; f < 4; ++f) {
            const int arow = wr + f * 16 + l16;
            const int aoff = arow * 32 + ((g ^ ((arow >> 1) & 3)) * 8);
            fah[f] = *reinterpret_cast<const bf16x8*>(&Ah[buf][aoff]);
            fal[f] = *reinterpret_cast<const bf16x8*>(&Al[buf][aoff]);
            const int brow = wc + f * 16 + l16;
            const int boff = brow * 32 + ((g ^ ((brow >> 1) & 3)) * 8);
            fbh[f] = *reinterpret_cast<const bf16x8*>(&Bh[buf][boff]);
            fbl[f] = *reinterpret_cast<const bf16x8*>(&Bl[buf][boff]);
        }
#pragma unroll
        for (int mf = 0; mf < 4; ++mf)
#pragma unroll
            for (int nf = 0; nf < 4; ++nf)
                acc[mf][nf] = __builtin_amdgcn_mfma_f32_16x16x32_bf16(fah[mf], fbh[nf], acc[mf][nf], 0, 0, 0);
#pragma unroll
        for (int mf = 0; mf < 4; ++mf)
#pragma unroll
            for (int nf = 0; nf < 4; ++nf)
                acc[mf][nf] = __builtin_amdgcn_mfma_f32_16x16x32_bf16(fal[mf], fbh[nf], acc[mf][nf], 0, 0, 0);
#pragma unroll
        for (int mf = 0; mf < 4; ++mf)
#pragma unroll
            for (int nf = 0; nf < 4; ++nf)
                acc[mf][nf] = __builtin_amdgcn_mfma_f32_16x16x32_bf16(fah[mf], fbl[nf], acc[mf][nf], 0, 0, 0);
    };

    stageA(0, k_lo); stageB(0, k_lo);
    int cur = 0;
    for (int ks = k_lo; ks < k_hi; ks += 32) {
        __syncthreads();
        const bool more = (ks + 32 < k_hi);
        if (more) { stageA(cur ^ 1, ks + 32); stageB(cur ^ 1, ks + 32); }
        compute(cur);
        cur ^= 1;
    }

    const int ncol0 = panel * 128;
#pragma unroll
    for (int mf = 0; mf < 4; ++mf) {
        const int row = m0 + wr + mf * 16 + g * 4;
#pragma unroll
        for (int nf = 0; nf < 4; ++nf) {
            const int col = ncol0 + wc + nf * 16 + l16;
#pragma unroll
            for (int r = 0; r < 4; ++r)
                gates[(size_t)(row + r) * 512 + col] = acc[mf][nf][r];
        }
    }
}

// ---------------- GRU elementwise (float4-vectorized; emits hi/lo planes) ----------------
__global__ __launch_bounds__(256) void gru_elem(
    const float* __restrict__ gates,
    const float* __restrict__ hcur,
    const float* __restrict__ b,     // (2,384) flat
    float*       __restrict__ hout,
    ushort_t*    __restrict__ outH,
    ushort_t*    __restrict__ outL)
{
    int u = blockIdx.x * 256 + threadIdx.x;      // over BN*32
    int n = u >> 5, jc = (u & 31) * 4;
    const float* gp = gates + (size_t)n * 512;
    float4 zp = *reinterpret_cast<const float4*>(&gp[jc]);
    float4 rp = *reinterpret_cast<const float4*>(&gp[128 + jc]);
    float4 xh = *reinterpret_cast<const float4*>(&gp[256 + jc]);
    float4 hh = *reinterpret_cast<const float4*>(&gp[384 + jc]);
    float4 hv = *reinterpret_cast<const float4*>(&hcur[(size_t)n * H_ + jc]);
    float4 ov;
    ushort4 oh, ol;
#pragma unroll
    for (int q = 0; q < 4; ++q) {
        int j = jc + q;
        float z  = 1.f / (1.f + expf(-((&zp.x)[q] + b[j] + b[384 + j])));
        float rr = 1.f / (1.f + expf(-((&rp.x)[q] + b[128 + j] + b[512 + j])));
        float cand = tanhf((&xh.x)[q] + b[256 + j] + rr * ((&hh.x)[q] + b[640 + j]));
        float o = z * (&hv.x)[q] + (1.f - z) * cand;
        (&ov.x)[q] = o;
        split2(o, (&oh.x)[q], (&ol.x)[q]);
    }
    const size_t o = (size_t)n * H_ + jc;
    *reinterpret_cast<float4*>(&hout[o]) = ov;
    *reinterpret_cast<ushort4*>(&outH[o]) = oh;
    *reinterpret_cast<ushort4*>(&outL[o]) = ol;
}

// ---------------- host orchestration ----------------
extern "C" void kernel_launch(void* const* d_in, const int* in_sizes, int n_in,
                              void* d_out, int out_size, void* d_ws, size_t ws_size,
                              hipStream_t stream) {
    const float* states = (const float*)d_in[0];
    const int*   eids   = (const int*)  d_in[1];
    const float* tw     = (const float*)d_in[2];   // (4,T,H,H)
    const float* tb     = (const float*)d_in[3];   // (4,T,H)
    const float* gW[4]  = { (const float*)d_in[4],  (const float*)d_in[7],
                            (const float*)d_in[10], (const float*)d_in[13] };
    const float* gU[4]  = { (const float*)d_in[5],  (const float*)d_in[8],
                            (const float*)d_in[11], (const float*)d_in[14] };
    const float* gb[4]  = { (const float*)d_in[6],  (const float*)d_in[9],
                            (const float*)d_in[12], (const float*)d_in[15] };
    float* out = (float*)d_out;

    const int KL[4]   = {256, 384, 256, 512};              // IN_DIM + 128 per layer
    const size_t KOFF[4] = {0, 512ull*256, 512ull*(256+384), 512ull*(256+384+256)};
    const size_t BT_TOT  = 512ull * (256 + 384 + 256 + 512);   // 720896 ushorts
    const size_t WT_L    = (size_t)T_ * H_ * H_;               // per-layer W plane
    const size_t PL      = (size_t)BN_ * H_;                   // plane elems

    char* ws = (char*)d_ws;
    float* bufA = (float*)ws; ws += PL * 4;
    float* bufB = (float*)ws; ws += PL * 4;
    float* bufC = (float*)ws; ws += PL * 4;
    float* agg  = (float*)ws; ws += PL * 4;
    char*  msgR = ws;         ws += (size_t)E_ * H_ * 4;    // 64MB: msg16 + gates alias
    ushort_t* stH = (ushort_t*)ws; ws += PL * 2;
    ushort_t* stL = (ushort_t*)ws; ws += PL * 2;
    ushort_t* paH = (ushort_t*)ws; ws += PL * 2;
    ushort_t* paL = (ushort_t*)ws; ws += PL * 2;
    ushort_t* pbH = (ushort_t*)ws; ws += PL * 2;
    ushort_t* pbL = (ushort_t*)ws; ws += PL * 2;
    ushort_t* pcH = (ushort_t*)ws; ws += PL * 2;
    ushort_t* pcL = (ushort_t*)ws; ws += PL * 2;
    ushort_t* agH = (ushort_t*)ws; ws += PL * 2;
    ushort_t* agL = (ushort_t*)ws; ws += PL * 2;
    ushort_t* bthAll = (ushort_t*)ws; ws += BT_TOT * 2;
    ushort_t* btlAll = (ushort_t*)ws; ws += BT_TOT * 2;
    ushort_t* wthAll = (ushort_t*)ws; ws += 4 * WT_L * 2;
    ushort_t* wtlAll = (ushort_t*)ws; ws += 4 * WT_L * 2;
    int*   perm  = (int*)ws;  ws += (size_t)E_ * 4;
    int*   rank  = (int*)ws;  ws += (size_t)E_ * 4;
    int*   tcnt  = (int*)ws;  ws += (size_t)BN_ * 4;
    int*   toff  = (int*)ws;  ws += (size_t)BN_ * 4;
    int*   tstart= (int*)ws;  ws += (size_t)(BN_ + 1) * 4;
    int*   meta  = (int*)ws;  ws += 64 * 4;
    ushort_t* msg16 = (ushort_t*)msgR;   // 33.5MB fp16
    float*    gates = (float*)msgR;      // 33.5MB fp32 (serial reuse)

    // ---- one-time sorts + splits ----
    hipMemsetAsync(meta, 0, 40 * sizeof(int), stream);
    hipMemsetAsync(tcnt, 0, BN_ * sizeof(int), stream);
    count_all<<<(E_ + 255) / 256, 256, 0, stream>>>(eids, meta, tcnt);
    scan_types<<<1, 1, 0, stream>>>(meta);
    scan_tgt  <<<1, 256, 0, stream>>>(tcnt, tstart, toff);
    scatter_all<<<(E_ + 255) / 256, 256, 0, stream>>>(eids, meta, toff, perm, rank);
    split_state<<<(int)(PL / 4 / 256), 256, 0, stream>>>(states, stH, stL);
    for (int lyr = 0; lyr < 4; ++lyr) {
        int K = KL[lyr];
        build_bt<<<(512 * K + 255) / 256, 256, 0, stream>>>(
            gW[lyr], gU[lyr], K - 128, K, bthAll + KOFF[lyr], btlAll + KOFF[lyr]);
        build_wt<<<((int)WT_L + 255) / 256, 256, 0, stream>>>(
            tw + lyr * WT_L, wthAll + lyr * WT_L, wtlAll + lyr * WT_L);
    }

    // step schedule: layers [0,0,0, 1, 2,2,2, 3]
    const int layer_of[8] = {0, 0, 0, 1, 2, 2, 2, 3};
    float*    target[8]  = {bufA, bufB, bufC, bufA, bufB, bufA, bufB, out};
    ushort_t* targetH[8] = {paH, pbH, pcH, paH, pbH, paH, pbH, paH};  // final: dummy
    ushort_t* targetL[8] = {paL, pbL, pcL, paL, pbL, paL, pbL, paL};

    const float* cur = states;
    const ushort_t* curH = stH; const ushort_t* curL = stL;
    const int edge_grid = E_ / EPB + T_;

    for (int s = 0; s < 8; ++s) {
        const int l = layer_of[s];
        edge_mfma<<<edge_grid, 256, 0, stream>>>(
            curH, curL, eids, perm, rank, meta,
            wthAll + l * WT_L, wtlAll + l * WT_L, tb + (size_t)l * T_ * H_, msg16);
        aggregate<<<BN_ / 8, 256, 0, stream>>>(msg16, tstart, agg, agH, agL);

        // A sources in order [res..., agg, cur]
        const ushort_t *h0, *l0, *h1, *l1, *h2, *l2, *h3, *l3;
        if (l == 0 || l == 2) {
            h0 = agH; l0 = agL; h1 = curH; l1 = curL;
            h2 = nullptr; l2 = nullptr; h3 = nullptr; l3 = nullptr;
        } else if (l == 1) {
            h0 = stH; l0 = stL; h1 = agH; l1 = agL; h2 = curH; l2 = curL;
            h3 = nullptr; l3 = nullptr;
        } else {
            h0 = stH; l0 = stL; h1 = pcH; l1 = pcL; h2 = agH; l2 = agL;
            h3 = curH; l3 = curL;
        }

        dim3 ggrid(BN_ / 128, 4);
        gates_mfma<<<ggrid, 256, 0, stream>>>(h0, l0, h1, l1, h2, l2, h3, l3,
                                              bthAll + KOFF[l], btlAll + KOFF[l],
                                              KL[l], gates);

        float* nxt = target[s];
        gru_elem<<<BN_ * 32 / 256, 256, 0, stream>>>(gates, cur, gb[l], nxt,
                                                     targetH[s], targetL[s]);
        cur = nxt; curH = targetH[s]; curL = targetL[s];
    }
}

// Round 11
// 656.912 us; speedup vs baseline: 1.3455x; 1.0996x over previous
//
#include <hip/hip_runtime.h>
#include <hip/hip_fp16.h>
#include <math.h>

#define B_  32
#define N_  512
#define H_  128
#define E_  131072
#define T_  9
#define BN_ (B_*N_)
#define EPB 64   // edges per block in edge MFMA GEMM (32KB LDS -> 5 blocks/CU)

typedef unsigned short ushort_t;
typedef __attribute__((ext_vector_type(8))) _Float16 f16x8;
typedef __attribute__((ext_vector_type(4))) float f32x4;

// split fp32 -> fp16 hi + fp16 lo. v ~= h + l with ~2^-22 rel err (|v| < 65504).
__device__ __forceinline__ void split2h(float v, ushort_t &h, ushort_t &l) {
    __half hh = __float2half(v);
    float r = v - __half2float(hh);
    __half ll = __float2half(r);
    h = __builtin_bit_cast(ushort_t, hh);
    l = __builtin_bit_cast(ushort_t, ll);
}

// k-slot swizzle baked into global weight layout (G21). phys slot of logical k.
__device__ __forceinline__ int kswz(int k, int n) {
    return (k & ~31) | (((((k >> 3) & 3) ^ ((n >> 1) & 3))) << 3) | (k & 7);
}

// meta layout (ints): [0..8]=cnt, [9..17]=start, [18..26]=off(atomic), [27..36]=cumBlocks(10)

// ---------------- fused histograms (type + target) ----------------
__global__ void count_all(const int* __restrict__ eids, int* __restrict__ meta,
                          int* __restrict__ tcnt) {
    __shared__ int lc[T_];
    if (threadIdx.x < T_) lc[threadIdx.x] = 0;
    __syncthreads();
    int e = blockIdx.x * 256 + threadIdx.x;
    if (e < E_) {
        int4 v = reinterpret_cast<const int4*>(eids)[e];
        atomicAdd(&lc[v.x], 1);
        atomicAdd(&tcnt[v.y * N_ + v.w], 1);
    }
    __syncthreads();
    if (threadIdx.x < T_ && lc[threadIdx.x]) atomicAdd(&meta[threadIdx.x], lc[threadIdx.x]);
}

__global__ void scan_types(int* meta) {
    int s = 0;
    for (int t = 0; t < T_; ++t) { meta[9 + t] = s; meta[18 + t] = s; s += meta[t]; }
    int cb = 0;
    for (int t = 0; t < T_; ++t) { meta[27 + t] = cb; cb += (meta[t] + EPB - 1) / EPB; }
    meta[27 + T_] = cb;
}

__global__ void scan_tgt(const int* __restrict__ tcnt, int* __restrict__ tstart,
                         int* __restrict__ toff) {
    __shared__ int bs[256];
    const int tid = threadIdx.x;
    const int chunk = BN_ / 256;   // 64
    const int base = tid * chunk;
    int s = 0;
    for (int i = 0; i < chunk; ++i) s += tcnt[base + i];
    bs[tid] = s;
    __syncthreads();
    if (tid == 0) { int acc = 0; for (int i = 0; i < 256; ++i) { int v = bs[i]; bs[i] = acc; acc += v; } }
    __syncthreads();
    int acc = bs[tid];
    for (int i = 0; i < chunk; ++i) {
        int v = tcnt[base + i];
        tstart[base + i] = acc; toff[base + i] = acc; acc += v;
    }
    if (tid == 255) tstart[BN_] = E_;
}

// ---------------- fused scatter (type perm + target rank) ----------------
__global__ void scatter_all(const int* __restrict__ eids, int* __restrict__ meta,
                            int* __restrict__ toff, int* __restrict__ perm,
                            int* __restrict__ rank) {
    __shared__ int lc[T_], lbase[T_];
    if (threadIdx.x < T_) lc[threadIdx.x] = 0;
    __syncthreads();
    int e = blockIdx.x * 256 + threadIdx.x;
    int4 v = {0, 0, 0, 0};
    int lp = 0;
    if (e < E_) { v = reinterpret_cast<const int4*>(eids)[e]; lp = atomicAdd(&lc[v.x], 1); }
    __syncthreads();
    if (threadIdx.x < T_ && lc[threadIdx.x])
        lbase[threadIdx.x] = atomicAdd(&meta[18 + threadIdx.x], lc[threadIdx.x]);
    __syncthreads();
    if (e < E_) {
        perm[lbase[v.x] + lp] = e;
        rank[e] = atomicAdd(&toff[v.y * N_ + v.w], 1);
    }
}

// ---------------- state split: fp32 (BN,H) -> fp16 hi/lo planes ----------------
__global__ __launch_bounds__(256) void split_state(const float* __restrict__ in,
                                                   ushort_t* __restrict__ hP,
                                                   ushort_t* __restrict__ lP) {
    int i = blockIdx.x * 256 + threadIdx.x;      // over BN*H/4
    float4 v = reinterpret_cast<const float4*>(in)[i];
    ushort4 h, l;
    split2h(v.x, h.x, l.x); split2h(v.y, h.y, l.y);
    split2h(v.z, h.z, l.z); split2h(v.w, h.w, l.w);
    reinterpret_cast<ushort4*>(hP)[i] = h;
    reinterpret_cast<ushort4*>(lP)[i] = l;
}

// ---------------- weight fp16 transpose for edge MFMA ----------------
// in: (T,H,H) = W[t][k][n]; out: (T,128,128) = [t][n][kswz(k,n)] fp16
__global__ void build_wt(const float* __restrict__ W, ushort_t* __restrict__ wt16) {
    int idx = blockIdx.x * 256 + threadIdx.x;
    if (idx >= T_ * H_ * H_) return;
    int t = idx / (H_ * H_);
    int rem = idx - t * H_ * H_;
    int n = rem >> 7, k = rem & 127;
    float v = W[(size_t)t * H_ * H_ + k * H_ + n];
    size_t o = (size_t)t * H_ * H_ + n * 128 + kswz(k, n);
    wt16[o] = __builtin_bit_cast(ushort_t, __float2half(v));
}

// ---------------- edge message GEMM via fp16x2 MFMA (64-edge blocks) ----------------
__global__ __launch_bounds__(256) void edge_mfma(
    const ushort_t* __restrict__ hH,   // (BN,H) fp16-hi plane of current state
    const ushort_t* __restrict__ hL,   // lo plane
    const int*   __restrict__ eids,
    const int*   __restrict__ perm,
    const int*   __restrict__ rank,
    const int*   __restrict__ meta,
    const ushort_t* __restrict__ wt16, // (T,128,128) [t][n][k swz] fp16
    const float* __restrict__ bias,    // (T,H)
    ushort_t*    __restrict__ msg16)   // (E,H) fp16, target-sorted
{
    __shared__ ushort_t Ah[2][EPB * 32], Al[2][EPB * 32];
    __shared__ ushort_t Bh[2][128 * 32];
    __shared__ int srcnode[EPB], outrow[EPB];
    __shared__ int info[3];
    const int tid = threadIdx.x;

    if (tid == 0) {
        int b = blockIdx.x;
        int nb = meta[27 + T_];
        if (b >= nb) info[0] = -1;
        else {
            int t = 0;
            while (b >= meta[27 + t + 1]) t++;
            int chunk = b - meta[27 + t];
            int c = meta[t] - chunk * EPB;
            info[0] = t;
            info[1] = meta[9 + t] + chunk * EPB;
            info[2] = (c > EPB) ? EPB : c;
        }
    }
    __syncthreads();
    const int t = info[0];
    if (t < 0) return;
    const int base = info[1], cnt = info[2];

    if (tid < EPB) {
        int e = perm[base + ((tid < cnt) ? tid : 0)];
        int eb = eids[e * 4 + 1];
        int es = eids[e * 4 + 2];
        srcnode[tid] = eb * N_ + es;
        outrow[tid]  = rank[e];
    }
    __syncthreads();

    const int w = tid >> 6, l = tid & 63;
    const int wr = (w >> 1) * 32, wc = (w & 1) * 64;
    const int l16 = l & 15, g = l >> 4;

    // A staging: lane (row=tid>>2, slot=tid&3); wave w covers rows 16w..16w+15
    const int arow_st = tid >> 2;
    const int aswz = ((tid & 3) ^ ((arow_st >> 1) & 3)) * 8;
    const int nodeReg = srcnode[arow_st];
    const int bw = w * 32;            // B staging: wave's 32 B-rows

    f32x4 acc[2][4];
#pragma unroll
    for (int i = 0; i < 2; ++i)
#pragma unroll
        for (int j = 0; j < 4; ++j) acc[i][j] = (f32x4){0.f, 0.f, 0.f, 0.f};

    auto stageA = [&](int buf, int k0) {
        const size_t off = (size_t)nodeReg * H_ + k0 + aswz;
        __builtin_amdgcn_global_load_lds(
            (const __attribute__((address_space(1))) void*)(hH + off),
            (__attribute__((address_space(3))) void*)&Ah[buf][w * 16 * 32], 16, 0, 0);
        __builtin_amdgcn_global_load_lds(
            (const __attribute__((address_space(1))) void*)(hL + off),
            (__attribute__((address_space(3))) void*)&Al[buf][w * 16 * 32], 16, 0, 0);
    };
    auto stageB = [&](int buf, int k0) {
#pragma unroll
        for (int q = 0; q < 2; ++q) {
            const int row = bw + q * 16 + (l >> 2);
            const size_t off = ((size_t)t * 128 + row) * 128 + k0 + (l & 3) * 8;
            __builtin_amdgcn_global_load_lds(
                (const __attribute__((address_space(1))) void*)(wt16 + off),
                (__attribute__((address_space(3))) void*)&Bh[buf][(bw + q * 16) * 32], 16, 0, 0);
        }
    };
    auto compute = [&](int buf) {
        f16x8 fah[2], fal[2], fbh[4];
#pragma unroll
        for (int f = 0; f < 2; ++f) {
            const int arow = wr + f * 16 + l16;
            const int aoff = arow * 32 + ((g ^ ((arow >> 1) & 3)) * 8);
            fah[f] = *reinterpret_cast<const f16x8*>(&Ah[buf][aoff]);
            fal[f] = *reinterpret_cast<const f16x8*>(&Al[buf][aoff]);
        }
#pragma unroll
        for (int f = 0; f < 4; ++f) {
            const int brow = wc + f * 16 + l16;
            const int boff = brow * 32 + ((g ^ ((brow >> 1) & 3)) * 8);
            fbh[f] = *reinterpret_cast<const f16x8*>(&Bh[buf][boff]);
        }
#pragma unroll
        for (int mf = 0; mf < 2; ++mf)
#pragma unroll
            for (int nf = 0; nf < 4; ++nf)
                acc[mf][nf] = __builtin_amdgcn_mfma_f32_16x16x32_f16(fah[mf], fbh[nf], acc[mf][nf], 0, 0, 0);
#pragma unroll
        for (int mf = 0; mf < 2; ++mf)
#pragma unroll
            for (int nf = 0; nf < 4; ++nf)
                acc[mf][nf] = __builtin_amdgcn_mfma_f32_16x16x32_f16(fal[mf], fbh[nf], acc[mf][nf], 0, 0, 0);
    };

    stageA(0, 0); stageB(0, 0);
    int cur = 0;
    for (int ks = 0; ks < 4; ++ks) {
        __syncthreads();
        const bool more = (ks + 1 < 4);
        if (more) { stageA(cur ^ 1, (ks + 1) * 32); stageB(cur ^ 1, (ks + 1) * 32); }
        compute(cur);
        cur ^= 1;
    }

    // epilogue: C/D layout col=lane&15, row=(lane>>4)*4+reg; fp16 store
#pragma unroll
    for (int mf = 0; mf < 2; ++mf) {
        const int rbase = wr + mf * 16 + g * 4;
#pragma unroll
        for (int nf = 0; nf < 4; ++nf) {
            const int col = wc + nf * 16 + l16;
            const float bv = bias[t * H_ + col];
#pragma unroll
            for (int r = 0; r < 4; ++r) {
                const int row = rbase + r;
                if (row < cnt)
                    msg16[(size_t)outrow[row] * H_ + col] =
                        __builtin_bit_cast(ushort_t, __float2half(acc[mf][nf][r] + bv));
            }
        }
    }
}

// ---------------- segmented aggregation (fp16 in; fp32 + fp16 hi/lo planes out) ----------------
__global__ __launch_bounds__(256) void aggregate(
    const ushort_t* __restrict__ msg16,
    const int*      __restrict__ tstart,
    float*          __restrict__ agg,
    ushort_t*       __restrict__ agH,
    ushort_t*       __restrict__ agL)
{
    const int n  = blockIdx.x * 8 + (threadIdx.x >> 5);
    const int jc = (threadIdx.x & 31) * 4;
    const int s = tstart[n], e_end = tstart[n + 1];
    float a0 = 0.f, a1 = 0.f, a2 = 0.f, a3 = 0.f;
    for (int i = s; i < e_end; ++i) {
        ushort4 u = *reinterpret_cast<const ushort4*>(&msg16[(size_t)i * H_ + jc]);
        a0 += __half2float(__builtin_bit_cast(__half, u.x));
        a1 += __half2float(__builtin_bit_cast(__half, u.y));
        a2 += __half2float(__builtin_bit_cast(__half, u.z));
        a3 += __half2float(__builtin_bit_cast(__half, u.w));
    }
    const size_t o = (size_t)n * H_ + jc;
    *reinterpret_cast<float4*>(&agg[o]) = make_float4(a0, a1, a2, a3);
    ushort4 h, l;
    split2h(a0, h.x, l.x); split2h(a1, h.y, l.y);
    split2h(a2, h.z, l.z); split2h(a3, h.w, l.w);
    *reinterpret_cast<ushort4*>(&agH[o]) = h;
    *reinterpret_cast<ushort4*>(&agL[o]) = l;
}

// ---------------- B-hat build: fp16 transpose of GRU weights (k-swizzled) ----------------
__global__ void build_bt(const float* __restrict__ W, const float* __restrict__ U,
                         const int Kx, const int K, ushort_t* __restrict__ bt16)
{
    int idx = blockIdx.x * 256 + threadIdx.x;
    if (idx >= 512 * K) return;
    int n = idx / K, k = idx - n * K;
    int p = n >> 7;
    float v;
    if (p < 2)       v = (k < Kx) ? W[(size_t)k * 384 + n] : U[(size_t)(k - Kx) * 384 + n];
    else if (p == 2) v = (k < Kx) ? W[(size_t)k * 384 + n] : 0.f;
    else             v = (k >= Kx) ? U[(size_t)(k - Kx) * 384 + (n - 128)] : 0.f;
    size_t o = (size_t)n * K + kswz(k, n);
    bt16[o] = __builtin_bit_cast(ushort_t, __float2half(v));
}

// ---------------- gates GEMM via fp16x2 MFMA: 128x128 tile, exact per-panel K ----------------
// panel = blockIdx.y: 0:z [0,K) | 1:r [0,K) | 2:xh [0,Kx) | 3:hh [Kx,K)
__global__ __launch_bounds__(256) void gates_mfma(
    const ushort_t* __restrict__ s0H, const ushort_t* __restrict__ s0L,
    const ushort_t* __restrict__ s1H, const ushort_t* __restrict__ s1L,
    const ushort_t* __restrict__ s2H, const ushort_t* __restrict__ s2L,
    const ushort_t* __restrict__ s3H, const ushort_t* __restrict__ s3L,
    const ushort_t* __restrict__ bt16,
    const int K, ushort_t* __restrict__ gates16)   // (BN,512) fp16
{
    __shared__ ushort_t Ah[2][128 * 32], Al[2][128 * 32];
    __shared__ ushort_t Bh[2][128 * 32];
    const ushort_t* sH[4] = {s0H, s1H, s2H, s3H};
    const ushort_t* sL[4] = {s0L, s1L, s2L, s3L};
    const int tid = threadIdx.x;
    const int m0 = blockIdx.x * 128;
    const int panel = blockIdx.y;
    const int Kx = K - 128;
    const int k_lo = (panel == 3) ? Kx : 0;
    const int k_hi = (panel == 2) ? Kx : K;
    const int w = tid >> 6, l = tid & 63;
    const int wr = (w >> 1) * 64, wc = (w & 1) * 64;
    const int l16 = l & 15, g = l >> 4;

    const int bw = w * 32;

    f32x4 acc[4][4];
#pragma unroll
    for (int i = 0; i < 4; ++i)
#pragma unroll
        for (int j = 0; j < 4; ++j) acc[i][j] = (f32x4){0.f, 0.f, 0.f, 0.f};

    auto stageA = [&](int buf, int kg0) {
        const ushort_t* spH = sH[kg0 >> 7];
        const ushort_t* spL = sL[kg0 >> 7];
        const int kc = kg0 & 127;
#pragma unroll
        for (int q = 0; q < 2; ++q) {
            const int row = q * 64 + (tid >> 2);
            const int kg = ((tid & 3) ^ ((row >> 1) & 3)) * 8;
            const size_t off = (size_t)(m0 + row) * H_ + kc + kg;
            __builtin_amdgcn_global_load_lds(
                (const __attribute__((address_space(1))) void*)(spH + off),
                (__attribute__((address_space(3))) void*)&Ah[buf][(q * 64 + w * 16) * 32], 16, 0, 0);
            __builtin_amdgcn_global_load_lds(
                (const __attribute__((address_space(1))) void*)(spL + off),
                (__attribute__((address_space(3))) void*)&Al[buf][(q * 64 + w * 16) * 32], 16, 0, 0);
        }
    };
    auto stageB = [&](int buf, int k0) {
#pragma unroll
        for (int q = 0; q < 2; ++q) {
            const int row = bw + q * 16 + (l >> 2);
            const size_t off = (size_t)(panel * 128 + row) * K + k0 + (l & 3) * 8;
            __builtin_amdgcn_global_load_lds(
                (const __attribute__((address_space(1))) void*)(bt16 + off),
                (__attribute__((address_space(3))) void*)&Bh[buf][(bw + q * 16) * 32], 16, 0, 0);
        }
    };
    auto compute = [&](int buf) {
        f16x8 fah[4], fal[4], fbh[4];
#pragma unroll
        for (int f = 0; f < 4; ++f) {
            const int arow = wr + f * 16 + l16;
            const int aoff = arow * 32 + ((g ^ ((arow >> 1) & 3)) * 8);
            fah[f] = *reinterpret_cast<const f16x8*>(&Ah[buf][aoff]);
            fal[f] = *reinterpret_cast<const f16x8*>(&Al[buf][aoff]);
            const int brow = wc + f * 16 + l16;
            const int boff = brow * 32 + ((g ^ ((brow >> 1) & 3)) * 8);
            fbh[f] = *reinterpret_cast<const f16x8*>(&Bh[buf][boff]);
        }
#pragma unroll
        for (int mf = 0; mf < 4; ++mf)
#pragma unroll
            for (int nf = 0; nf < 4; ++nf)
                acc[mf][nf] = __builtin_amdgcn_mfma_f32_16x16x32_f16(fah[mf], fbh[nf], acc[mf][nf], 0, 0, 0);
#pragma unroll
        for (int mf = 0; mf < 4; ++mf)
#pragma unroll
            for (int nf = 0; nf < 4; ++nf)
                acc[mf][nf] = __builtin_amdgcn_mfma_f32_16x16x32_f16(fal[mf], fbh[nf], acc[mf][nf], 0, 0, 0);
    };

    stageA(0, k_lo); stageB(0, k_lo);
    int cur = 0;
    for (int ks = k_lo; ks < k_hi; ks += 32) {
        __syncthreads();
        const bool more = (ks + 32 < k_hi);
        if (more) { stageA(cur ^ 1, ks + 32); stageB(cur ^ 1, ks + 32); }
        compute(cur);
        cur ^= 1;
    }

    const int ncol0 = panel * 128;
#pragma unroll
    for (int mf = 0; mf < 4; ++mf) {
        const int row = m0 + wr + mf * 16 + g * 4;
#pragma unroll
        for (int nf = 0; nf < 4; ++nf) {
            const int col = ncol0 + wc + nf * 16 + l16;
#pragma unroll
            for (int r = 0; r < 4; ++r)
                gates16[(size_t)(row + r) * 512 + col] =
                    __builtin_bit_cast(ushort_t, __float2half(acc[mf][nf][r]));
        }
    }
}

// ---------------- GRU elementwise (fp16 gates in; fp32 + fp16 hi/lo planes out) ----------------
__global__ __launch_bounds__(256) void gru_elem(
    const ushort_t* __restrict__ gates16,
    const float* __restrict__ hcur,
    const float* __restrict__ b,     // (2,384) flat
    float*       __restrict__ hout,
    ushort_t*    __restrict__ outH,
    ushort_t*    __restrict__ outL)
{
    int u = blockIdx.x * 256 + threadIdx.x;      // over BN*32
    int n = u >> 5, jc = (u & 31) * 4;
    const ushort_t* gp = gates16 + (size_t)n * 512;
    ushort4 zpu = *reinterpret_cast<const ushort4*>(&gp[jc]);
    ushort4 rpu = *reinterpret_cast<const ushort4*>(&gp[128 + jc]);
    ushort4 xhu = *reinterpret_cast<const ushort4*>(&gp[256 + jc]);
    ushort4 hhu = *reinterpret_cast<const ushort4*>(&gp[384 + jc]);
    float4 hv = *reinterpret_cast<const float4*>(&hcur[(size_t)n * H_ + jc]);
    float4 ov;
    ushort4 oh, ol;
#pragma unroll
    for (int q = 0; q < 4; ++q) {
        int j = jc + q;
        float zp = __half2float(__builtin_bit_cast(__half, (&zpu.x)[q]));
        float rp = __half2float(__builtin_bit_cast(__half, (&rpu.x)[q]));
        float xh = __half2float(__builtin_bit_cast(__half, (&xhu.x)[q]));
        float hh = __half2float(__builtin_bit_cast(__half, (&hhu.x)[q]));
        float z  = 1.f / (1.f + expf(-(zp + b[j] + b[384 + j])));
        float rr = 1.f / (1.f + expf(-(rp + b[128 + j] + b[512 + j])));
        float cand = tanhf(xh + b[256 + j] + rr * (hh + b[640 + j]));
        float o = z * (&hv.x)[q] + (1.f - z) * cand;
        (&ov.x)[q] = o;
        split2h(o, (&oh.x)[q], (&ol.x)[q]);
    }
    const size_t o = (size_t)n * H_ + jc;
    *reinterpret_cast<float4*>(&hout[o]) = ov;
    *reinterpret_cast<ushort4*>(&outH[o]) = oh;
    *reinterpret_cast<ushort4*>(&outL[o]) = ol;
}

// ---------------- host orchestration ----------------
extern "C" void kernel_launch(void* const* d_in, const int* in_sizes, int n_in,
                              void* d_out, int out_size, void* d_ws, size_t ws_size,
                              hipStream_t stream) {
    const float* states = (const float*)d_in[0];
    const int*   eids   = (const int*)  d_in[1];
    const float* tw     = (const float*)d_in[2];   // (4,T,H,H)
    const float* tb     = (const float*)d_in[3];   // (4,T,H)
    const float* gW[4]  = { (const float*)d_in[4],  (const float*)d_in[7],
                            (const float*)d_in[10], (const float*)d_in[13] };
    const float* gU[4]  = { (const float*)d_in[5],  (const float*)d_in[8],
                            (const float*)d_in[11], (const float*)d_in[14] };
    const float* gb[4]  = { (const float*)d_in[6],  (const float*)d_in[9],
                            (const float*)d_in[12], (const float*)d_in[15] };
    float* out = (float*)d_out;

    const int KL[4]   = {256, 384, 256, 512};              // IN_DIM + 128 per layer
    const size_t KOFF[4] = {0, 512ull*256, 512ull*(256+384), 512ull*(256+384+256)};
    const size_t BT_TOT  = 512ull * (256 + 384 + 256 + 512);   // 720896 ushorts
    const size_t WT_L    = (size_t)T_ * H_ * H_;               // per-layer W plane
    const size_t PL      = (size_t)BN_ * H_;                   // plane elems

    char* ws = (char*)d_ws;
    float* bufA = (float*)ws; ws += PL * 4;
    float* bufB = (float*)ws; ws += PL * 4;
    float* bufC = (float*)ws; ws += PL * 4;
    float* agg  = (float*)ws; ws += PL * 4;
    char*  msgR = ws;         ws += (size_t)E_ * H_ * 2;    // 33.5MB: msg16
    char*  gatR = ws;         ws += (size_t)BN_ * 512 * 2;  // 16.75MB: gates16
    ushort_t* stH = (ushort_t*)ws; ws += PL * 2;
    ushort_t* stL = (ushort_t*)ws; ws += PL * 2;
    ushort_t* paH = (ushort_t*)ws; ws += PL * 2;
    ushort_t* paL = (ushort_t*)ws; ws += PL * 2;
    ushort_t* pbH = (ushort_t*)ws; ws += PL * 2;
    ushort_t* pbL = (ushort_t*)ws; ws += PL * 2;
    ushort_t* pcH = (ushort_t*)ws; ws += PL * 2;
    ushort_t* pcL = (ushort_t*)ws; ws += PL * 2;
    ushort_t* agH = (ushort_t*)ws; ws += PL * 2;
    ushort_t* agL = (ushort_t*)ws; ws += PL * 2;
    ushort_t* btAll = (ushort_t*)ws; ws += BT_TOT * 2;
    ushort_t* wtAll = (ushort_t*)ws; ws += 4 * WT_L * 2;
    int*   perm  = (int*)ws;  ws += (size_t)E_ * 4;
    int*   rank  = (int*)ws;  ws += (size_t)E_ * 4;
    int*   tcnt  = (int*)ws;  ws += (size_t)BN_ * 4;
    int*   toff  = (int*)ws;  ws += (size_t)BN_ * 4;
    int*   tstart= (int*)ws;  ws += (size_t)(BN_ + 1) * 4;
    int*   meta  = (int*)ws;  ws += 64 * 4;
    ushort_t* msg16   = (ushort_t*)msgR;
    ushort_t* gates16 = (ushort_t*)gatR;

    // ---- one-time sorts + splits ----
    hipMemsetAsync(meta, 0, 40 * sizeof(int), stream);
    hipMemsetAsync(tcnt, 0, BN_ * sizeof(int), stream);
    count_all<<<(E_ + 255) / 256, 256, 0, stream>>>(eids, meta, tcnt);
    scan_types<<<1, 1, 0, stream>>>(meta);
    scan_tgt  <<<1, 256, 0, stream>>>(tcnt, tstart, toff);
    scatter_all<<<(E_ + 255) / 256, 256, 0, stream>>>(eids, meta, toff, perm, rank);
    split_state<<<(int)(PL / 4 / 256), 256, 0, stream>>>(states, stH, stL);
    for (int lyr = 0; lyr < 4; ++lyr) {
        int K = KL[lyr];
        build_bt<<<(512 * K + 255) / 256, 256, 0, stream>>>(
            gW[lyr], gU[lyr], K - 128, K, btAll + KOFF[lyr]);
        build_wt<<<((int)WT_L + 255) / 256, 256, 0, stream>>>(
            tw + lyr * WT_L, wtAll + lyr * WT_L);
    }

    // step schedule: layers [0,0,0, 1, 2,2,2, 3]
    const int layer_of[8] = {0, 0, 0, 1, 2, 2, 2, 3};
    float*    target[8]  = {bufA, bufB, bufC, bufA, bufB, bufA, bufB, out};
    ushort_t* targetH[8] = {paH, pbH, pcH, paH, pbH, paH, pbH, paH};
    ushort_t* targetL[8] = {paL, pbL, pcL, paL, pbL, paL, pbL, paL};

    const float* cur = states;
    const ushort_t* curH = stH; const ushort_t* curL = stL;
    const int edge_grid = E_ / EPB + T_;

    for (int s = 0; s < 8; ++s) {
        const int l = layer_of[s];
        edge_mfma<<<edge_grid, 256, 0, stream>>>(
            curH, curL, eids, perm, rank, meta,
            wtAll + l * WT_L, tb + (size_t)l * T_ * H_, msg16);
        aggregate<<<BN_ / 8, 256, 0, stream>>>(msg16, tstart, agg, agH, agL);

        // A sources in order [res..., agg, cur]
        const ushort_t *h0, *l0, *h1, *l1, *h2, *l2, *h3, *l3;
        if (l == 0 || l == 2) {
            h0 = agH; l0 = agL; h1 = curH; l1 = curL;
            h2 = nullptr; l2 = nullptr; h3 = nullptr; l3 = nullptr;
        } else if (l == 1) {
            h0 = stH; l0 = stL; h1 = agH; l1 = agL; h2 = curH; l2 = curL;
            h3 = nullptr; l3 = nullptr;
        } else {
            h0 = stH; l0 = stL; h1 = pcH; l1 = pcL; h2 = agH; l2 = agL;
            h3 = curH; l3 = curL;
        }

        dim3 ggrid(BN_ / 128, 4);
        gates_mfma<<<ggrid, 256, 0, stream>>>(h0, l0, h1, l1, h2, l2, h3, l3,
                                              btAll + KOFF[l], KL[l], gates16);

        float* nxt = target[s];
        gru_elem<<<BN_ * 32 / 256, 256, 0, stream>>>(gates16, cur, gb[l], nxt,
                                                     targetH[s], targetL[s]);
        cur = nxt; curH = targetH[s]; curL = targetL[s];
    }
}

// Round 12
// 548.816 us; speedup vs baseline: 1.6105x; 1.1970x over previous
//
#include <hip/hip_runtime.h>
#include <hip/hip_fp16.h>
#include <math.h>

#define B_  32
#define N_  512
#define H_  128
#define E_  131072
#define T_  9
#define BN_ (B_*N_)
#define EPB 64   // edges per block in edge MFMA GEMM (24KB LDS -> 6 blocks/CU)

typedef unsigned short ushort_t;
typedef __attribute__((ext_vector_type(8))) _Float16 f16x8;
typedef __attribute__((ext_vector_type(4))) float f32x4;

// k-slot swizzle baked into global weight layout (G21). phys slot of logical k.
__device__ __forceinline__ int kswz(int k, int n) {
    return (k & ~31) | (((((k >> 3) & 3) ^ ((n >> 1) & 3))) << 3) | (k & 7);
}

// meta layout (ints): [0..8]=cnt, [9..17]=start, [18..26]=off(atomic), [27..36]=cumBlocks(10)

// ---------------- fused histograms (type + target) ----------------
__global__ void count_all(const int* __restrict__ eids, int* __restrict__ meta,
                          int* __restrict__ tcnt) {
    __shared__ int lc[T_];
    if (threadIdx.x < T_) lc[threadIdx.x] = 0;
    __syncthreads();
    int e = blockIdx.x * 256 + threadIdx.x;
    if (e < E_) {
        int4 v = reinterpret_cast<const int4*>(eids)[e];
        atomicAdd(&lc[v.x], 1);
        atomicAdd(&tcnt[v.y * N_ + v.w], 1);
    }
    __syncthreads();
    if (threadIdx.x < T_ && lc[threadIdx.x]) atomicAdd(&meta[threadIdx.x], lc[threadIdx.x]);
}

__global__ void scan_types(int* meta) {
    int s = 0;
    for (int t = 0; t < T_; ++t) { meta[9 + t] = s; meta[18 + t] = s; s += meta[t]; }
    int cb = 0;
    for (int t = 0; t < T_; ++t) { meta[27 + t] = cb; cb += (meta[t] + EPB - 1) / EPB; }
    meta[27 + T_] = cb;
}

__global__ void scan_tgt(const int* __restrict__ tcnt, int* __restrict__ tstart,
                         int* __restrict__ toff) {
    __shared__ int bs[256];
    const int tid = threadIdx.x;
    const int chunk = BN_ / 256;   // 64
    const int base = tid * chunk;
    int s = 0;
    for (int i = 0; i < chunk; ++i) s += tcnt[base + i];
    bs[tid] = s;
    __syncthreads();
    if (tid == 0) { int acc = 0; for (int i = 0; i < 256; ++i) { int v = bs[i]; bs[i] = acc; acc += v; } }
    __syncthreads();
    int acc = bs[tid];
    for (int i = 0; i < chunk; ++i) {
        int v = tcnt[base + i];
        tstart[base + i] = acc; toff[base + i] = acc; acc += v;
    }
    if (tid == 255) tstart[BN_] = E_;
}

// ---------------- fused scatter (type perm + target rank) ----------------
__global__ void scatter_all(const int* __restrict__ eids, int* __restrict__ meta,
                            int* __restrict__ toff, int* __restrict__ perm,
                            int* __restrict__ rank) {
    __shared__ int lc[T_], lbase[T_];
    if (threadIdx.x < T_) lc[threadIdx.x] = 0;
    __syncthreads();
    int e = blockIdx.x * 256 + threadIdx.x;
    int4 v = {0, 0, 0, 0};
    int lp = 0;
    if (e < E_) { v = reinterpret_cast<const int4*>(eids)[e]; lp = atomicAdd(&lc[v.x], 1); }
    __syncthreads();
    if (threadIdx.x < T_ && lc[threadIdx.x])
        lbase[threadIdx.x] = atomicAdd(&meta[18 + threadIdx.x], lc[threadIdx.x]);
    __syncthreads();
    if (e < E_) {
        perm[lbase[v.x] + lp] = e;
        rank[e] = atomicAdd(&toff[v.y * N_ + v.w], 1);
    }
}

// ---------------- state cast: fp32 (BN,H) -> fp16 plane ----------------
__global__ __launch_bounds__(256) void cast_state(const float* __restrict__ in,
                                                  ushort_t* __restrict__ hP) {
    int i = blockIdx.x * 256 + threadIdx.x;      // over BN*H/4
    float4 v = reinterpret_cast<const float4*>(in)[i];
    ushort4 h;
    h.x = __builtin_bit_cast(ushort_t, __float2half(v.x));
    h.y = __builtin_bit_cast(ushort_t, __float2half(v.y));
    h.z = __builtin_bit_cast(ushort_t, __float2half(v.z));
    h.w = __builtin_bit_cast(ushort_t, __float2half(v.w));
    reinterpret_cast<ushort4*>(hP)[i] = h;
}

// ---------------- weight fp16 transpose for edge MFMA ----------------
// in: (T,H,H) = W[t][k][n]; out: (T,128,128) = [t][n][kswz(k,n)] fp16
__global__ void build_wt(const float* __restrict__ W, ushort_t* __restrict__ wt16) {
    int idx = blockIdx.x * 256 + threadIdx.x;
    if (idx >= T_ * H_ * H_) return;
    int t = idx / (H_ * H_);
    int rem = idx - t * H_ * H_;
    int n = rem >> 7, k = rem & 127;
    float v = W[(size_t)t * H_ * H_ + k * H_ + n];
    size_t o = (size_t)t * H_ * H_ + n * 128 + kswz(k, n);
    wt16[o] = __builtin_bit_cast(ushort_t, __float2half(v));
}

// ---------------- edge message GEMM via fp16 MFMA (64-edge blocks) ----------------
__global__ __launch_bounds__(256) void edge_mfma(
    const ushort_t* __restrict__ hP,   // (BN,H) fp16 plane of current state
    const int*   __restrict__ eids,
    const int*   __restrict__ perm,
    const int*   __restrict__ rank,
    const int*   __restrict__ meta,
    const ushort_t* __restrict__ wt16, // (T,128,128) [t][n][k swz] fp16
    const float* __restrict__ bias,    // (T,H)
    ushort_t*    __restrict__ msg16)   // (E,H) fp16, target-sorted
{
    __shared__ ushort_t Ah[2][EPB * 32];
    __shared__ ushort_t Bh[2][128 * 32];
    __shared__ int srcnode[EPB], outrow[EPB];
    __shared__ int info[3];
    const int tid = threadIdx.x;

    if (tid == 0) {
        int b = blockIdx.x;
        int nb = meta[27 + T_];
        if (b >= nb) info[0] = -1;
        else {
            int t = 0;
            while (b >= meta[27 + t + 1]) t++;
            int chunk = b - meta[27 + t];
            int c = meta[t] - chunk * EPB;
            info[0] = t;
            info[1] = meta[9 + t] + chunk * EPB;
            info[2] = (c > EPB) ? EPB : c;
        }
    }
    __syncthreads();
    const int t = info[0];
    if (t < 0) return;
    const int base = info[1], cnt = info[2];

    if (tid < EPB) {
        int e = perm[base + ((tid < cnt) ? tid : 0)];
        int eb = eids[e * 4 + 1];
        int es = eids[e * 4 + 2];
        srcnode[tid] = eb * N_ + es;
        outrow[tid]  = rank[e];
    }
    __syncthreads();

    const int w = tid >> 6, l = tid & 63;
    const int wr = (w >> 1) * 32, wc = (w & 1) * 64;
    const int l16 = l & 15, g = l >> 4;

    // A staging: lane (row=tid>>2, slot=tid&3); wave w covers rows 16w..16w+15
    const int arow_st = tid >> 2;
    const int aswz = ((tid & 3) ^ ((arow_st >> 1) & 3)) * 8;
    const int nodeReg = srcnode[arow_st];
    const int bw = w * 32;            // B staging: wave's 32 B-rows

    f32x4 acc[2][4];
#pragma unroll
    for (int i = 0; i < 2; ++i)
#pragma unroll
        for (int j = 0; j < 4; ++j) acc[i][j] = (f32x4){0.f, 0.f, 0.f, 0.f};

    auto stageA = [&](int buf, int k0) {
        const size_t off = (size_t)nodeReg * H_ + k0 + aswz;
        __builtin_amdgcn_global_load_lds(
            (const __attribute__((address_space(1))) void*)(hP + off),
            (__attribute__((address_space(3))) void*)&Ah[buf][w * 16 * 32], 16, 0, 0);
    };
    auto stageB = [&](int buf, int k0) {
#pragma unroll
        for (int q = 0; q < 2; ++q) {
            const int row = bw + q * 16 + (l >> 2);
            const size_t off = ((size_t)t * 128 + row) * 128 + k0 + (l & 3) * 8;
            __builtin_amdgcn_global_load_lds(
                (const __attribute__((address_space(1))) void*)(wt16 + off),
                (__attribute__((address_space(3))) void*)&Bh[buf][(bw + q * 16) * 32], 16, 0, 0);
        }
    };
    auto compute = [&](int buf) {
        f16x8 fah[2], fbh[4];
#pragma unroll
        for (int f = 0; f < 2; ++f) {
            const int arow = wr + f * 16 + l16;
            const int aoff = arow * 32 + ((g ^ ((arow >> 1) & 3)) * 8);
            fah[f] = *reinterpret_cast<const f16x8*>(&Ah[buf][aoff]);
        }
#pragma unroll
        for (int f = 0; f < 4; ++f) {
            const int brow = wc + f * 16 + l16;
            const int boff = brow * 32 + ((g ^ ((brow >> 1) & 3)) * 8);
            fbh[f] = *reinterpret_cast<const f16x8*>(&Bh[buf][boff]);
        }
#pragma unroll
        for (int mf = 0; mf < 2; ++mf)
#pragma unroll
            for (int nf = 0; nf < 4; ++nf)
                acc[mf][nf] = __builtin_amdgcn_mfma_f32_16x16x32_f16(fah[mf], fbh[nf], acc[mf][nf], 0, 0, 0);
    };

    stageA(0, 0); stageB(0, 0);
    int cur = 0;
    for (int ks = 0; ks < 4; ++ks) {
        __syncthreads();
        const bool more = (ks + 1 < 4);
        if (more) { stageA(cur ^ 1, (ks + 1) * 32); stageB(cur ^ 1, (ks + 1) * 32); }
        compute(cur);
        cur ^= 1;
    }

    // epilogue: C/D layout col=lane&15, row=(lane>>4)*4+reg; fp16 store
#pragma unroll
    for (int mf = 0; mf < 2; ++mf) {
        const int rbase = wr + mf * 16 + g * 4;
#pragma unroll
        for (int nf = 0; nf < 4; ++nf) {
            const int col = wc + nf * 16 + l16;
            const float bv = bias[t * H_ + col];
#pragma unroll
            for (int r = 0; r < 4; ++r) {
                const int row = rbase + r;
                if (row < cnt)
                    msg16[(size_t)outrow[row] * H_ + col] =
                        __builtin_bit_cast(ushort_t, __float2half(acc[mf][nf][r] + bv));
            }
        }
    }
}

// ---------------- segmented aggregation (fp16 in; fp32 + fp16 plane out) ----------------
__global__ __launch_bounds__(256) void aggregate(
    const ushort_t* __restrict__ msg16,
    const int*      __restrict__ tstart,
    float*          __restrict__ agg,
    ushort_t*       __restrict__ agP)
{
    const int n  = blockIdx.x * 8 + (threadIdx.x >> 5);
    const int jc = (threadIdx.x & 31) * 4;
    const int s = tstart[n], e_end = tstart[n + 1];
    float a0 = 0.f, a1 = 0.f, a2 = 0.f, a3 = 0.f;
    for (int i = s; i < e_end; ++i) {
        ushort4 u = *reinterpret_cast<const ushort4*>(&msg16[(size_t)i * H_ + jc]);
        a0 += __half2float(__builtin_bit_cast(__half, u.x));
        a1 += __half2float(__builtin_bit_cast(__half, u.y));
        a2 += __half2float(__builtin_bit_cast(__half, u.z));
        a3 += __half2float(__builtin_bit_cast(__half, u.w));
    }
    const size_t o = (size_t)n * H_ + jc;
    *reinterpret_cast<float4*>(&agg[o]) = make_float4(a0, a1, a2, a3);
    ushort4 h;
    h.x = __builtin_bit_cast(ushort_t, __float2half(a0));
    h.y = __builtin_bit_cast(ushort_t, __float2half(a1));
    h.z = __builtin_bit_cast(ushort_t, __float2half(a2));
    h.w = __builtin_bit_cast(ushort_t, __float2half(a3));
    *reinterpret_cast<ushort4*>(&agP[o]) = h;
}

// ---------------- B-hat build: fp16 transpose of GRU weights (k-swizzled) ----------------
__global__ void build_bt(const float* __restrict__ W, const float* __restrict__ U,
                         const int Kx, const int K, ushort_t* __restrict__ bt16)
{
    int idx = blockIdx.x * 256 + threadIdx.x;
    if (idx >= 512 * K) return;
    int n = idx / K, k = idx - n * K;
    int p = n >> 7;
    float v;
    if (p < 2)       v = (k < Kx) ? W[(size_t)k * 384 + n] : U[(size_t)(k - Kx) * 384 + n];
    else if (p == 2) v = (k < Kx) ? W[(size_t)k * 384 + n] : 0.f;
    else             v = (k >= Kx) ? U[(size_t)(k - Kx) * 384 + (n - 128)] : 0.f;
    size_t o = (size_t)n * K + kswz(k, n);
    bt16[o] = __builtin_bit_cast(ushort_t, __float2half(v));
}

// ---------------- gates GEMM via fp16 MFMA: 128x128 tile, exact per-panel K ----------------
// panel = blockIdx.y: 0:z [0,K) | 1:r [0,K) | 2:xh [0,Kx) | 3:hh [Kx,K)
__global__ __launch_bounds__(256) void gates_mfma(
    const ushort_t* __restrict__ s0P, const ushort_t* __restrict__ s1P,
    const ushort_t* __restrict__ s2P, const ushort_t* __restrict__ s3P,
    const ushort_t* __restrict__ bt16,
    const int K, ushort_t* __restrict__ gates16)   // (BN,512) fp16
{
    __shared__ ushort_t Ah[2][128 * 32];
    __shared__ ushort_t Bh[2][128 * 32];
    const ushort_t* sP[4] = {s0P, s1P, s2P, s3P};
    const int tid = threadIdx.x;
    const int m0 = blockIdx.x * 128;
    const int panel = blockIdx.y;
    const int Kx = K - 128;
    const int k_lo = (panel == 3) ? Kx : 0;
    const int k_hi = (panel == 2) ? Kx : K;
    const int w = tid >> 6, l = tid & 63;
    const int wr = (w >> 1) * 64, wc = (w & 1) * 64;
    const int l16 = l & 15, g = l >> 4;

    const int bw = w * 32;

    f32x4 acc[4][4];
#pragma unroll
    for (int i = 0; i < 4; ++i)
#pragma unroll
        for (int j = 0; j < 4; ++j) acc[i][j] = (f32x4){0.f, 0.f, 0.f, 0.f};

    auto stageA = [&](int buf, int kg0) {
        const ushort_t* sp = sP[kg0 >> 7];
        const int kc = kg0 & 127;
#pragma unroll
        for (int q = 0; q < 2; ++q) {
            const int row = q * 64 + (tid >> 2);
            const int kg = ((tid & 3) ^ ((row >> 1) & 3)) * 8;
            const size_t off = (size_t)(m0 + row) * H_ + kc + kg;
            __builtin_amdgcn_global_load_lds(
                (const __attribute__((address_space(1))) void*)(sp + off),
                (__attribute__((address_space(3))) void*)&Ah[buf][(q * 64 + w * 16) * 32], 16, 0, 0);
        }
    };
    auto stageB = [&](int buf, int k0) {
#pragma unroll
        for (int q = 0; q < 2; ++q) {
            const int row = bw + q * 16 + (l >> 2);
            const size_t off = (size_t)(panel * 128 + row) * K + k0 + (l & 3) * 8;
            __builtin_amdgcn_global_load_lds(
                (const __attribute__((address_space(1))) void*)(bt16 + off),
                (__attribute__((address_space(3))) void*)&Bh[buf][(bw + q * 16) * 32], 16, 0, 0);
        }
    };
    auto compute = [&](int buf) {
        f16x8 fah[4], fbh[4];
#pragma unroll
        for (int f = 0; f < 4; ++f) {
            const int arow = wr + f * 16 + l16;
            const int aoff = arow * 32 + ((g ^ ((arow >> 1) & 3)) * 8);
            fah[f] = *reinterpret_cast<const f16x8*>(&Ah[buf][aoff]);
            const int brow = wc + f * 16 + l16;
            const int boff = brow * 32 + ((g ^ ((brow >> 1) & 3)) * 8);
            fbh[f] = *reinterpret_cast<const f16x8*>(&Bh[buf][boff]);
        }
#pragma unroll
        for (int mf = 0; mf < 4; ++mf)
#pragma unroll
            for (int nf = 0; nf < 4; ++nf)
                acc[mf][nf] = __builtin_amdgcn_mfma_f32_16x16x32_f16(fah[mf], fbh[nf], acc[mf][nf], 0, 0, 0);
    };

    stageA(0, k_lo); stageB(0, k_lo);
    int cur = 0;
    for (int ks = k_lo; ks < k_hi; ks += 32) {
        __syncthreads();
        const bool more = (ks + 32 < k_hi);
        if (more) { stageA(cur ^ 1, ks + 32); stageB(cur ^ 1, ks + 32); }
        compute(cur);
        cur ^= 1;
    }

    const int ncol0 = panel * 128;
#pragma unroll
    for (int mf = 0; mf < 4; ++mf) {
        const int row = m0 + wr + mf * 16 + g * 4;
#pragma unroll
        for (int nf = 0; nf < 4; ++nf) {
            const int col = ncol0 + wc + nf * 16 + l16;
#pragma unroll
            for (int r = 0; r < 4; ++r)
                gates16[(size_t)(row + r) * 512 + col] =
                    __builtin_bit_cast(ushort_t, __float2half(acc[mf][nf][r]));
        }
    }
}

// ---------------- GRU elementwise (fp16 gates in; fp32 + fp16 plane out) ----------------
__global__ __launch_bounds__(256) void gru_elem(
    const ushort_t* __restrict__ gates16,
    const float* __restrict__ hcur,
    const float* __restrict__ b,     // (2,384) flat
    float*       __restrict__ hout,
    ushort_t*    __restrict__ outP)
{
    int u = blockIdx.x * 256 + threadIdx.x;      // over BN*32
    int n = u >> 5, jc = (u & 31) * 4;
    const ushort_t* gp = gates16 + (size_t)n * 512;
    ushort4 zpu = *reinterpret_cast<const ushort4*>(&gp[jc]);
    ushort4 rpu = *reinterpret_cast<const ushort4*>(&gp[128 + jc]);
    ushort4 xhu = *reinterpret_cast<const ushort4*>(&gp[256 + jc]);
    ushort4 hhu = *reinterpret_cast<const ushort4*>(&gp[384 + jc]);
    float4 hv = *reinterpret_cast<const float4*>(&hcur[(size_t)n * H_ + jc]);
    float4 ov;
    ushort4 oh;
#pragma unroll
    for (int q = 0; q < 4; ++q) {
        int j = jc + q;
        float zp = __half2float(__builtin_bit_cast(__half, (&zpu.x)[q]));
        float rp = __half2float(__builtin_bit_cast(__half, (&rpu.x)[q]));
        float xh = __half2float(__builtin_bit_cast(__half, (&xhu.x)[q]));
        float hh = __half2float(__builtin_bit_cast(__half, (&hhu.x)[q]));
        float z  = 1.f / (1.f + expf(-(zp + b[j] + b[384 + j])));
        float rr = 1.f / (1.f + expf(-(rp + b[128 + j] + b[512 + j])));
        float cand = tanhf(xh + b[256 + j] + rr * (hh + b[640 + j]));
        float o = z * (&hv.x)[q] + (1.f - z) * cand;
        (&ov.x)[q] = o;
        (&oh.x)[q] = __builtin_bit_cast(ushort_t, __float2half(o));
    }
    const size_t o = (size_t)n * H_ + jc;
    *reinterpret_cast<float4*>(&hout[o]) = ov;
    *reinterpret_cast<ushort4*>(&outP[o]) = oh;
}

// ---------------- host orchestration ----------------
extern "C" void kernel_launch(void* const* d_in, const int* in_sizes, int n_in,
                              void* d_out, int out_size, void* d_ws, size_t ws_size,
                              hipStream_t stream) {
    const float* states = (const float*)d_in[0];
    const int*   eids   = (const int*)  d_in[1];
    const float* tw     = (const float*)d_in[2];   // (4,T,H,H)
    const float* tb     = (const float*)d_in[3];   // (4,T,H)
    const float* gW[4]  = { (const float*)d_in[4],  (const float*)d_in[7],
                            (const float*)d_in[10], (const float*)d_in[13] };
    const float* gU[4]  = { (const float*)d_in[5],  (const float*)d_in[8],
                            (const float*)d_in[11], (const float*)d_in[14] };
    const float* gb[4]  = { (const float*)d_in[6],  (const float*)d_in[9],
                            (const float*)d_in[12], (const float*)d_in[15] };
    float* out = (float*)d_out;

    const int KL[4]   = {256, 384, 256, 512};              // IN_DIM + 128 per layer
    const size_t KOFF[4] = {0, 512ull*256, 512ull*(256+384), 512ull*(256+384+256)};
    const size_t BT_TOT  = 512ull * (256 + 384 + 256 + 512);   // 720896 ushorts
    const size_t WT_L    = (size_t)T_ * H_ * H_;               // per-layer W plane
    const size_t PL      = (size_t)BN_ * H_;                   // plane elems

    char* ws = (char*)d_ws;
    float* bufA = (float*)ws; ws += PL * 4;
    float* bufB = (float*)ws; ws += PL * 4;
    float* bufC = (float*)ws; ws += PL * 4;
    float* agg  = (float*)ws; ws += PL * 4;
    char*  msgR = ws;         ws += (size_t)E_ * H_ * 2;    // 33.5MB: msg16
    char*  gatR = ws;         ws += (size_t)BN_ * 512 * 2;  // 16.75MB: gates16
    ushort_t* stP = (ushort_t*)ws; ws += PL * 2;
    ushort_t* paP = (ushort_t*)ws; ws += PL * 2;
    ushort_t* pbP = (ushort_t*)ws; ws += PL * 2;
    ushort_t* pcP = (ushort_t*)ws; ws += PL * 2;
    ushort_t* agP = (ushort_t*)ws; ws += PL * 2;
    ushort_t* btAll = (ushort_t*)ws; ws += BT_TOT * 2;
    ushort_t* wtAll = (ushort_t*)ws; ws += 4 * WT_L * 2;
    int*   perm  = (int*)ws;  ws += (size_t)E_ * 4;
    int*   rank  = (int*)ws;  ws += (size_t)E_ * 4;
    int*   tcnt  = (int*)ws;  ws += (size_t)BN_ * 4;
    int*   toff  = (int*)ws;  ws += (size_t)BN_ * 4;
    int*   tstart= (int*)ws;  ws += (size_t)(BN_ + 1) * 4;
    int*   meta  = (int*)ws;  ws += 64 * 4;
    ushort_t* msg16   = (ushort_t*)msgR;
    ushort_t* gates16 = (ushort_t*)gatR;

    // ---- one-time sorts + casts ----
    hipMemsetAsync(meta, 0, 40 * sizeof(int), stream);
    hipMemsetAsync(tcnt, 0, BN_ * sizeof(int), stream);
    count_all<<<(E_ + 255) / 256, 256, 0, stream>>>(eids, meta, tcnt);
    scan_types<<<1, 1, 0, stream>>>(meta);
    scan_tgt  <<<1, 256, 0, stream>>>(tcnt, tstart, toff);
    scatter_all<<<(E_ + 255) / 256, 256, 0, stream>>>(eids, meta, toff, perm, rank);
    cast_state<<<(int)(PL / 4 / 256), 256, 0, stream>>>(states, stP);
    for (int lyr = 0; lyr < 4; ++lyr) {
        int K = KL[lyr];
        build_bt<<<(512 * K + 255) / 256, 256, 0, stream>>>(
            gW[lyr], gU[lyr], K - 128, K, btAll + KOFF[lyr]);
        build_wt<<<((int)WT_L + 255) / 256, 256, 0, stream>>>(
            tw + lyr * WT_L, wtAll + lyr * WT_L);
    }

    // step schedule: layers [0,0,0, 1, 2,2,2, 3]
    const int layer_of[8] = {0, 0, 0, 1, 2, 2, 2, 3};
    float*    target[8]  = {bufA, bufB, bufC, bufA, bufB, bufA, bufB, out};
    ushort_t* targetP[8] = {paP, pbP, pcP, paP, pbP, paP, pbP, paP};

    const float* cur = states;
    const ushort_t* curP = stP;
    const int edge_grid = E_ / EPB + T_;

    for (int s = 0; s < 8; ++s) {
        const int l = layer_of[s];
        edge_mfma<<<edge_grid, 256, 0, stream>>>(
            curP, eids, perm, rank, meta,
            wtAll + l * WT_L, tb + (size_t)l * T_ * H_, msg16);
        aggregate<<<BN_ / 8, 256, 0, stream>>>(msg16, tstart, agg, agP);

        // A sources in order [res..., agg, cur]
        const ushort_t *p0, *p1, *p2, *p3;
        if (l == 0 || l == 2)      { p0 = agP; p1 = curP; p2 = nullptr; p3 = nullptr; }
        else if (l == 1)           { p0 = stP; p1 = agP;  p2 = curP;    p3 = nullptr; }
        else                       { p0 = stP; p1 = pcP;  p2 = agP;     p3 = curP;    }

        dim3 ggrid(BN_ / 128, 4);
        gates_mfma<<<ggrid, 256, 0, stream>>>(p0, p1, p2, p3,
                                              btAll + KOFF[l], KL[l], gates16);

        float* nxt = target[s];
        gru_elem<<<BN_ * 32 / 256, 256, 0, stream>>>(gates16, cur, gb[l], nxt,
                                                     targetP[s]);
        cur = nxt; curP = targetP[s];
    }
}

// Round 13
// 532.319 us; speedup vs baseline: 1.6604x; 1.0310x over previous
//
#include <hip/hip_runtime.h>
#include <hip/hip_fp16.h>
#include <math.h>

#define B_  32
#define N_  512
#define H_  128
#define E_  131072
#define T_  9
#define BN_ (B_*N_)
#define EPB 64   // edges per block in edge MFMA GEMM (24KB LDS)

typedef unsigned short ushort_t;
typedef __attribute__((ext_vector_type(8))) _Float16 f16x8;
typedef __attribute__((ext_vector_type(4))) float f32x4;

// k-slot swizzle baked into global weight layout (G21). phys slot of logical k.
__device__ __forceinline__ int kswz(int k, int n) {
    return (k & ~31) | (((((k >> 3) & 3) ^ ((n >> 1) & 3))) << 3) | (k & 7);
}

// meta layout (ints): [0..8]=cnt, [9..17]=start, [18..26]=off(atomic), [27..36]=cumBlocks(10)

// ---------------- fused histograms (type + target) ----------------
__global__ void count_all(const int* __restrict__ eids, int* __restrict__ meta,
                          int* __restrict__ tcnt) {
    __shared__ int lc[T_];
    if (threadIdx.x < T_) lc[threadIdx.x] = 0;
    __syncthreads();
    int e = blockIdx.x * 256 + threadIdx.x;
    if (e < E_) {
        int4 v = reinterpret_cast<const int4*>(eids)[e];
        atomicAdd(&lc[v.x], 1);
        atomicAdd(&tcnt[v.y * N_ + v.w], 1);
    }
    __syncthreads();
    if (threadIdx.x < T_ && lc[threadIdx.x]) atomicAdd(&meta[threadIdx.x], lc[threadIdx.x]);
}

// scan_tgt also performs the tiny type-scan (tid 0)
__global__ void scan_all(const int* __restrict__ tcnt, int* __restrict__ tstart,
                         int* __restrict__ toff, int* __restrict__ meta) {
    __shared__ int bs[256];
    const int tid = threadIdx.x;
    if (tid == 0) {
        int s = 0;
        for (int t = 0; t < T_; ++t) { meta[9 + t] = s; meta[18 + t] = s; s += meta[t]; }
        int cb = 0;
        for (int t = 0; t < T_; ++t) { meta[27 + t] = cb; cb += (meta[t] + EPB - 1) / EPB; }
        meta[27 + T_] = cb;
    }
    const int chunk = BN_ / 256;   // 64
    const int base = tid * chunk;
    int s = 0;
    for (int i = 0; i < chunk; ++i) s += tcnt[base + i];
    bs[tid] = s;
    __syncthreads();
    if (tid == 0) { int acc = 0; for (int i = 0; i < 256; ++i) { int v = bs[i]; bs[i] = acc; acc += v; } }
    __syncthreads();
    int acc = bs[tid];
    for (int i = 0; i < chunk; ++i) {
        int v = tcnt[base + i];
        tstart[base + i] = acc; toff[base + i] = acc; acc += v;
    }
    if (tid == 255) tstart[BN_] = E_;
}

// ---------------- fused scatter (type perm + target rank) ----------------
__global__ void scatter_all(const int* __restrict__ eids, int* __restrict__ meta,
                            int* __restrict__ toff, int* __restrict__ perm,
                            int* __restrict__ rank) {
    __shared__ int lc[T_], lbase[T_];
    if (threadIdx.x < T_) lc[threadIdx.x] = 0;
    __syncthreads();
    int e = blockIdx.x * 256 + threadIdx.x;
    int4 v = {0, 0, 0, 0};
    int lp = 0;
    if (e < E_) { v = reinterpret_cast<const int4*>(eids)[e]; lp = atomicAdd(&lc[v.x], 1); }
    __syncthreads();
    if (threadIdx.x < T_ && lc[threadIdx.x])
        lbase[threadIdx.x] = atomicAdd(&meta[18 + threadIdx.x], lc[threadIdx.x]);
    __syncthreads();
    if (e < E_) {
        perm[lbase[v.x] + lp] = e;
        rank[e] = atomicAdd(&toff[v.y * N_ + v.w], 1);
    }
}

// ---------------- state cast: fp32 (BN,H) -> fp16 plane ----------------
__global__ __launch_bounds__(256) void cast_state(const float* __restrict__ in,
                                                  ushort_t* __restrict__ hP) {
    int i = blockIdx.x * 256 + threadIdx.x;      // over BN*H/4
    float4 v = reinterpret_cast<const float4*>(in)[i];
    ushort4 h;
    h.x = __builtin_bit_cast(ushort_t, __float2half(v.x));
    h.y = __builtin_bit_cast(ushort_t, __float2half(v.y));
    h.z = __builtin_bit_cast(ushort_t, __float2half(v.z));
    h.w = __builtin_bit_cast(ushort_t, __float2half(v.w));
    reinterpret_cast<ushort4*>(hP)[i] = h;
}

// ---------------- weight fp16 transpose for edge MFMA (all 4 layers, one launch) ----------------
// in: (4,T,H,H) = W[l][t][k][n]; out: (4,T,128,128) = [l][t][n][kswz(k,n)] fp16
__global__ void build_wt(const float* __restrict__ W, ushort_t* __restrict__ wt16) {
    int idx = blockIdx.x * 256 + threadIdx.x;
    if (idx >= 4 * T_ * H_ * H_) return;
    int lt = idx / (H_ * H_);                 // layer*T + t combined plane
    int rem = idx - lt * H_ * H_;
    int n = rem >> 7, k = rem & 127;
    float v = W[(size_t)lt * H_ * H_ + k * H_ + n];
    size_t o = (size_t)lt * H_ * H_ + n * 128 + kswz(k, n);
    wt16[o] = __builtin_bit_cast(ushort_t, __float2half(v));
}

// ---------------- B-hat build: fp16 transpose of GRU weights, all layers ----------------
struct BtArgs {
    const float* W[4];
    const float* U[4];
    unsigned long long off[4];
    int K[4];
};
__global__ void build_bt(BtArgs a, ushort_t* __restrict__ bt16) {
    const int lyr = blockIdx.y;
    const int K = a.K[lyr];
    const int Kx = K - 128;
    int idx = blockIdx.x * 256 + threadIdx.x;
    if (idx >= 512 * K) return;
    int n = idx / K, k = idx - n * K;
    int p = n >> 7;
    const float* W = a.W[lyr];
    const float* U = a.U[lyr];
    float v;
    if (p < 2)       v = (k < Kx) ? W[(size_t)k * 384 + n] : U[(size_t)(k - Kx) * 384 + n];
    else if (p == 2) v = (k < Kx) ? W[(size_t)k * 384 + n] : 0.f;
    else             v = (k >= Kx) ? U[(size_t)(k - Kx) * 384 + (n - 128)] : 0.f;
    size_t o = a.off[lyr] + (size_t)n * K + kswz(k, n);
    bt16[o] = __builtin_bit_cast(ushort_t, __float2half(v));
}

// ---------------- edge message GEMM via fp16 MFMA (64-edge blocks) ----------------
__global__ __launch_bounds__(256) void edge_mfma(
    const ushort_t* __restrict__ hP,   // (BN,H) fp16 plane of current state
    const int*   __restrict__ eids,
    const int*   __restrict__ perm,
    const int*   __restrict__ rank,
    const int*   __restrict__ meta,
    const ushort_t* __restrict__ wt16, // (T,128,128) [t][n][k swz] fp16
    const float* __restrict__ bias,    // (T,H)
    ushort_t*    __restrict__ msg16)   // (E,H) fp16, target-sorted
{
    __shared__ ushort_t Ah[2][EPB * 32];
    __shared__ ushort_t Bh[2][128 * 32];
    __shared__ int srcnode[EPB], outrow[EPB];
    __shared__ int info[3];
    const int tid = threadIdx.x;

    if (tid == 0) {
        int b = blockIdx.x;
        int nb = meta[27 + T_];
        if (b >= nb) info[0] = -1;
        else {
            int t = 0;
            while (b >= meta[27 + t + 1]) t++;
            int chunk = b - meta[27 + t];
            int c = meta[t] - chunk * EPB;
            info[0] = t;
            info[1] = meta[9 + t] + chunk * EPB;
            info[2] = (c > EPB) ? EPB : c;
        }
    }
    __syncthreads();
    const int t = info[0];
    if (t < 0) return;
    const int base = info[1], cnt = info[2];

    if (tid < EPB) {
        int e = perm[base + ((tid < cnt) ? tid : 0)];
        int eb = eids[e * 4 + 1];
        int es = eids[e * 4 + 2];
        srcnode[tid] = eb * N_ + es;
        outrow[tid]  = rank[e];
    }
    __syncthreads();

    const int w = tid >> 6, l = tid & 63;
    const int wr = (w >> 1) * 32, wc = (w & 1) * 64;
    const int l16 = l & 15, g = l >> 4;

    // A staging: lane (row=tid>>2, slot=tid&3); wave w covers rows 16w..16w+15
    const int arow_st = tid >> 2;
    const int aswz = ((tid & 3) ^ ((arow_st >> 1) & 3)) * 8;
    const int nodeReg = srcnode[arow_st];
    const int bw = w * 32;            // B staging: wave's 32 B-rows

    f32x4 acc[2][4];
#pragma unroll
    for (int i = 0; i < 2; ++i)
#pragma unroll
        for (int j = 0; j < 4; ++j) acc[i][j] = (f32x4){0.f, 0.f, 0.f, 0.f};

    auto stageA = [&](int buf, int k0) {
        const size_t off = (size_t)nodeReg * H_ + k0 + aswz;
        __builtin_amdgcn_global_load_lds(
            (const __attribute__((address_space(1))) void*)(hP + off),
            (__attribute__((address_space(3))) void*)&Ah[buf][w * 16 * 32], 16, 0, 0);
    };
    auto stageB = [&](int buf, int k0) {
#pragma unroll
        for (int q = 0; q < 2; ++q) {
            const int row = bw + q * 16 + (l >> 2);
            const size_t off = ((size_t)t * 128 + row) * 128 + k0 + (l & 3) * 8;
            __builtin_amdgcn_global_load_lds(
                (const __attribute__((address_space(1))) void*)(wt16 + off),
                (__attribute__((address_space(3))) void*)&Bh[buf][(bw + q * 16) * 32], 16, 0, 0);
        }
    };
    auto compute = [&](int buf) {
        f16x8 fah[2], fbh[4];
#pragma unroll
        for (int f = 0; f < 2; ++f) {
            const int arow = wr + f * 16 + l16;
            const int aoff = arow * 32 + ((g ^ ((arow >> 1) & 3)) * 8);
            fah[f] = *reinterpret_cast<const f16x8*>(&Ah[buf][aoff]);
        }
#pragma unroll
        for (int f = 0; f < 4; ++f) {
            const int brow = wc + f * 16 + l16;
            const int boff = brow * 32 + ((g ^ ((brow >> 1) & 3)) * 8);
            fbh[f] = *reinterpret_cast<const f16x8*>(&Bh[buf][boff]);
        }
#pragma unroll
        for (int mf = 0; mf < 2; ++mf)
#pragma unroll
            for (int nf = 0; nf < 4; ++nf)
                acc[mf][nf] = __builtin_amdgcn_mfma_f32_16x16x32_f16(fah[mf], fbh[nf], acc[mf][nf], 0, 0, 0);
    };

    stageA(0, 0); stageB(0, 0);
    int cur = 0;
    for (int ks = 0; ks < 4; ++ks) {
        __syncthreads();
        const bool more = (ks + 1 < 4);
        if (more) { stageA(cur ^ 1, (ks + 1) * 32); stageB(cur ^ 1, (ks + 1) * 32); }
        compute(cur);
        cur ^= 1;
    }

    // epilogue: C/D layout col=lane&15, row=(lane>>4)*4+reg; fp16 store
#pragma unroll
    for (int mf = 0; mf < 2; ++mf) {
        const int rbase = wr + mf * 16 + g * 4;
#pragma unroll
        for (int nf = 0; nf < 4; ++nf) {
            const int col = wc + nf * 16 + l16;
            const float bv = bias[t * H_ + col];
#pragma unroll
            for (int r = 0; r < 4; ++r) {
                const int row = rbase + r;
                if (row < cnt)
                    msg16[(size_t)outrow[row] * H_ + col] =
                        __builtin_bit_cast(ushort_t, __float2half(acc[mf][nf][r] + bv));
            }
        }
    }
}

// ---------------- segmented aggregation (fp16 in; fp16 plane out only) ----------------
__global__ __launch_bounds__(256) void aggregate(
    const ushort_t* __restrict__ msg16,
    const int*      __restrict__ tstart,
    ushort_t*       __restrict__ agP)
{
    const int n  = blockIdx.x * 8 + (threadIdx.x >> 5);
    const int jc = (threadIdx.x & 31) * 4;
    const int s = tstart[n], e_end = tstart[n + 1];
    float a0 = 0.f, a1 = 0.f, a2 = 0.f, a3 = 0.f;
    for (int i = s; i < e_end; ++i) {
        ushort4 u = *reinterpret_cast<const ushort4*>(&msg16[(size_t)i * H_ + jc]);
        a0 += __half2float(__builtin_bit_cast(__half, u.x));
        a1 += __half2float(__builtin_bit_cast(__half, u.y));
        a2 += __half2float(__builtin_bit_cast(__half, u.z));
        a3 += __half2float(__builtin_bit_cast(__half, u.w));
    }
    ushort4 h;
    h.x = __builtin_bit_cast(ushort_t, __float2half(a0));
    h.y = __builtin_bit_cast(ushort_t, __float2half(a1));
    h.z = __builtin_bit_cast(ushort_t, __float2half(a2));
    h.w = __builtin_bit_cast(ushort_t, __float2half(a3));
    *reinterpret_cast<ushort4*>(&agP[(size_t)n * H_ + jc]) = h;
}

// ---------------- gates GEMM via fp16 MFMA: 64x128 tile, exact per-panel K ----------------
// panel = blockIdx.y: 0:z [0,K) | 1:r [0,K) | 2:xh [0,Kx) | 3:hh [Kx,K)
// 64-row blocks -> grid (256,4) = 1024 blocks for 4 waves/SIMD TLP.
__global__ __launch_bounds__(256) void gates_mfma(
    const ushort_t* __restrict__ s0P, const ushort_t* __restrict__ s1P,
    const ushort_t* __restrict__ s2P, const ushort_t* __restrict__ s3P,
    const ushort_t* __restrict__ bt16,
    const int K, ushort_t* __restrict__ gates16)   // (BN,512) fp16
{
    __shared__ ushort_t Ah[2][64 * 32];
    __shared__ ushort_t Bh[2][128 * 32];
    const ushort_t* sP[4] = {s0P, s1P, s2P, s3P};
    const int tid = threadIdx.x;
    const int m0 = blockIdx.x * 64;
    const int panel = blockIdx.y;
    const int Kx = K - 128;
    const int k_lo = (panel == 3) ? Kx : 0;
    const int k_hi = (panel == 2) ? Kx : K;
    const int w = tid >> 6, l = tid & 63;
    const int wr = (w >> 1) * 32, wc = (w & 1) * 64;
    const int l16 = l & 15, g = l >> 4;

    // A staging: lane (row=tid>>2, slot=tid&3); wave w covers rows 16w..16w+15
    const int arow_st = tid >> 2;
    const int aswz = ((tid & 3) ^ ((arow_st >> 1) & 3)) * 8;
    const int bw = w * 32;

    f32x4 acc[2][4];
#pragma unroll
    for (int i = 0; i < 2; ++i)
#pragma unroll
        for (int j = 0; j < 4; ++j) acc[i][j] = (f32x4){0.f, 0.f, 0.f, 0.f};

    auto stageA = [&](int buf, int kg0) {
        const ushort_t* sp = sP[kg0 >> 7];
        const size_t off = (size_t)(m0 + arow_st) * H_ + (kg0 & 127) + aswz;
        __builtin_amdgcn_global_load_lds(
            (const __attribute__((address_space(1))) void*)(sp + off),
            (__attribute__((address_space(3))) void*)&Ah[buf][w * 16 * 32], 16, 0, 0);
    };
    auto stageB = [&](int buf, int k0) {
#pragma unroll
        for (int q = 0; q < 2; ++q) {
            const int row = bw + q * 16 + (l >> 2);
            const size_t off = (size_t)(panel * 128 + row) * K + k0 + (l & 3) * 8;
            __builtin_amdgcn_global_load_lds(
                (const __attribute__((address_space(1))) void*)(bt16 + off),
                (__attribute__((address_space(3))) void*)&Bh[buf][(bw + q * 16) * 32], 16, 0, 0);
        }
    };
    auto compute = [&](int buf) {
        f16x8 fah[2], fbh[4];
#pragma unroll
        for (int f = 0; f < 2; ++f) {
            const int arow = wr + f * 16 + l16;
            const int aoff = arow * 32 + ((g ^ ((arow >> 1) & 3)) * 8);
            fah[f] = *reinterpret_cast<const f16x8*>(&Ah[buf][aoff]);
        }
#pragma unroll
        for (int f = 0; f < 4; ++f) {
            const int brow = wc + f * 16 + l16;
            const int boff = brow * 32 + ((g ^ ((brow >> 1) & 3)) * 8);
            fbh[f] = *reinterpret_cast<const f16x8*>(&Bh[buf][boff]);
        }
#pragma unroll
        for (int mf = 0; mf < 2; ++mf)
#pragma unroll
            for (int nf = 0; nf < 4; ++nf)
                acc[mf][nf] = __builtin_amdgcn_mfma_f32_16x16x32_f16(fah[mf], fbh[nf], acc[mf][nf], 0, 0, 0);
    };

    stageA(0, k_lo); stageB(0, k_lo);
    int cur = 0;
    for (int ks = k_lo; ks < k_hi; ks += 32) {
        __syncthreads();
        const bool more = (ks + 32 < k_hi);
        if (more) { stageA(cur ^ 1, ks + 32); stageB(cur ^ 1, ks + 32); }
        compute(cur);
        cur ^= 1;
    }

    const int ncol0 = panel * 128;
#pragma unroll
    for (int mf = 0; mf < 2; ++mf) {
        const int row = m0 + wr + mf * 16 + g * 4;
#pragma unroll
        for (int nf = 0; nf < 4; ++nf) {
            const int col = ncol0 + wc + nf * 16 + l16;
#pragma unroll
            for (int r = 0; r < 4; ++r)
                gates16[(size_t)(row + r) * 512 + col] =
                    __builtin_bit_cast(ushort_t, __float2half(acc[mf][nf][r]));
        }
    }
}

// ---------------- GRU elementwise (fp16 gates in; fp32 + fp16 plane out) ----------------
__global__ __launch_bounds__(256) void gru_elem(
    const ushort_t* __restrict__ gates16,
    const float* __restrict__ hcur,
    const float* __restrict__ b,     // (2,384) flat
    float*       __restrict__ hout,
    ushort_t*    __restrict__ outP)
{
    int u = blockIdx.x * 256 + threadIdx.x;      // over BN*32
    int n = u >> 5, jc = (u & 31) * 4;
    const ushort_t* gp = gates16 + (size_t)n * 512;
    ushort4 zpu = *reinterpret_cast<const ushort4*>(&gp[jc]);
    ushort4 rpu = *reinterpret_cast<const ushort4*>(&gp[128 + jc]);
    ushort4 xhu = *reinterpret_cast<const ushort4*>(&gp[256 + jc]);
    ushort4 hhu = *reinterpret_cast<const ushort4*>(&gp[384 + jc]);
    float4 hv = *reinterpret_cast<const float4*>(&hcur[(size_t)n * H_ + jc]);
    float4 ov;
    ushort4 oh;
#pragma unroll
    for (int q = 0; q < 4; ++q) {
        int j = jc + q;
        float zp = __half2float(__builtin_bit_cast(__half, (&zpu.x)[q]));
        float rp = __half2float(__builtin_bit_cast(__half, (&rpu.x)[q]));
        float xh = __half2float(__builtin_bit_cast(__half, (&xhu.x)[q]));
        float hh = __half2float(__builtin_bit_cast(__half, (&hhu.x)[q]));
        float z  = 1.f / (1.f + expf(-(zp + b[j] + b[384 + j])));
        float rr = 1.f / (1.f + expf(-(rp + b[128 + j] + b[512 + j])));
        float cand = tanhf(xh + b[256 + j] + rr * (hh + b[640 + j]));
        float o = z * (&hv.x)[q] + (1.f - z) * cand;
        (&ov.x)[q] = o;
        (&oh.x)[q] = __builtin_bit_cast(ushort_t, __float2half(o));
    }
    const size_t o = (size_t)n * H_ + jc;
    *reinterpret_cast<float4*>(&hout[o]) = ov;
    *reinterpret_cast<ushort4*>(&outP[o]) = oh;
}

// ---------------- host orchestration ----------------
extern "C" void kernel_launch(void* const* d_in, const int* in_sizes, int n_in,
                              void* d_out, int out_size, void* d_ws, size_t ws_size,
                              hipStream_t stream) {
    const float* states = (const float*)d_in[0];
    const int*   eids   = (const int*)  d_in[1];
    const float* tw     = (const float*)d_in[2];   // (4,T,H,H)
    const float* tb     = (const float*)d_in[3];   // (4,T,H)
    const float* gW[4]  = { (const float*)d_in[4],  (const float*)d_in[7],
                            (const float*)d_in[10], (const float*)d_in[13] };
    const float* gU[4]  = { (const float*)d_in[5],  (const float*)d_in[8],
                            (const float*)d_in[11], (const float*)d_in[14] };
    const float* gb[4]  = { (const float*)d_in[6],  (const float*)d_in[9],
                            (const float*)d_in[12], (const float*)d_in[15] };
    float* out = (float*)d_out;

    const int KL[4]   = {256, 384, 256, 512};              // IN_DIM + 128 per layer
    const size_t KOFF[4] = {0, 512ull*256, 512ull*(256+384), 512ull*(256+384+256)};
    const size_t BT_TOT  = 512ull * (256 + 384 + 256 + 512);   // 720896 ushorts
    const size_t WT_L    = (size_t)T_ * H_ * H_;               // per-layer W plane
    const size_t PL      = (size_t)BN_ * H_;                   // plane elems

    char* ws = (char*)d_ws;
    float* bufA = (float*)ws; ws += PL * 4;
    float* bufB = (float*)ws; ws += PL * 4;
    float* bufC = (float*)ws; ws += PL * 4;
    char*  msgR = ws;         ws += (size_t)E_ * H_ * 2;    // 33.5MB: msg16
    char*  gatR = ws;         ws += (size_t)BN_ * 512 * 2;  // 16.75MB: gates16
    ushort_t* stP = (ushort_t*)ws; ws += PL * 2;
    ushort_t* paP = (ushort_t*)ws; ws += PL * 2;
    ushort_t* pbP = (ushort_t*)ws; ws += PL * 2;
    ushort_t* pcP = (ushort_t*)ws; ws += PL * 2;
    ushort_t* agP = (ushort_t*)ws; ws += PL * 2;
    ushort_t* btAll = (ushort_t*)ws; ws += BT_TOT * 2;
    ushort_t* wtAll = (ushort_t*)ws; ws += 4 * WT_L * 2;
    int*   perm  = (int*)ws;  ws += (size_t)E_ * 4;
    int*   rank  = (int*)ws;  ws += (size_t)E_ * 4;
    int*   tcnt  = (int*)ws;  ws += (size_t)BN_ * 4;
    int*   toff  = (int*)ws;  ws += (size_t)BN_ * 4;
    int*   tstart= (int*)ws;  ws += (size_t)(BN_ + 1) * 4;
    int*   meta  = (int*)ws;  ws += 64 * 4;
    ushort_t* msg16   = (ushort_t*)msgR;
    ushort_t* gates16 = (ushort_t*)gatR;

    // ---- one-time sorts + casts (batched) ----
    hipMemsetAsync(meta, 0, 40 * sizeof(int), stream);
    hipMemsetAsync(tcnt, 0, BN_ * sizeof(int), stream);
    count_all<<<(E_ + 255) / 256, 256, 0, stream>>>(eids, meta, tcnt);
    scan_all  <<<1, 256, 0, stream>>>(tcnt, tstart, toff, meta);
    scatter_all<<<(E_ + 255) / 256, 256, 0, stream>>>(eids, meta, toff, perm, rank);
    cast_state<<<(int)(PL / 4 / 256), 256, 0, stream>>>(states, stP);

    BtArgs bta;
    for (int lyr = 0; lyr < 4; ++lyr) {
        bta.W[lyr] = gW[lyr]; bta.U[lyr] = gU[lyr];
        bta.off[lyr] = KOFF[lyr]; bta.K[lyr] = KL[lyr];
    }
    build_bt<<<dim3((512 * 512 + 255) / 256, 4), 256, 0, stream>>>(bta, btAll);
    build_wt<<<(4 * (int)WT_L + 255) / 256, 256, 0, stream>>>(tw, wtAll);

    // step schedule: layers [0,0,0, 1, 2,2,2, 3]
    const int layer_of[8] = {0, 0, 0, 1, 2, 2, 2, 3};
    float*    target[8]  = {bufA, bufB, bufC, bufA, bufB, bufA, bufB, out};
    ushort_t* targetP[8] = {paP, pbP, pcP, paP, pbP, paP, pbP, paP};

    const float* cur = states;
    const ushort_t* curP = stP;
    const int edge_grid = E_ / EPB + T_;

    for (int s = 0; s < 8; ++s) {
        const int l = layer_of[s];
        edge_mfma<<<edge_grid, 256, 0, stream>>>(
            curP, eids, perm, rank, meta,
            wtAll + l * WT_L, tb + (size_t)l * T_ * H_, msg16);
        aggregate<<<BN_ / 8, 256, 0, stream>>>(msg16, tstart, agP);

        // A sources in order [res..., agg, cur]
        const ushort_t *p0, *p1, *p2, *p3;
        if (l == 0 || l == 2)      { p0 = agP; p1 = curP; p2 = nullptr; p3 = nullptr; }
        else if (l == 1)           { p0 = stP; p1 = agP;  p2 = curP;    p3 = nullptr; }
        else                       { p0 = stP; p1 = pcP;  p2 = agP;     p3 = curP;    }

        dim3 ggrid(BN_ / 64, 4);
        gates_mfma<<<ggrid, 256, 0, stream>>>(p0, p1, p2, p3,
                                              btAll + KOFF[l], KL[l], gates16);

        float* nxt = target[s];
        gru_elem<<<BN_ * 32 / 256, 256, 0, stream>>>(gates16, cur, gb[l], nxt,
                                                     targetP[s]);
        cur = nxt; curP = targetP[s];
    }
}